// Round 14
// baseline (487.785 us; speedup 1.0000x reference)
//
#include <hip/hip_runtime.h>

constexpr float kEps = 1e-5f;

typedef _Float16 h2 __attribute__((ext_vector_type(2)));
typedef float f2v __attribute__((ext_vector_type(2)));
typedef short bf16x8 __attribute__((ext_vector_type(8)));
typedef float f32x4v __attribute__((ext_vector_type(4)));

__device__ __forceinline__ unsigned short f2bf(float x) {
  unsigned int u = __float_as_uint(x);
  unsigned int r = (u + 0x7fffu + ((u >> 16) & 1u)) >> 16;
  return (unsigned short)r;
}
__device__ __forceinline__ float bflo(unsigned int u) { return __uint_as_float(u << 16); }
__device__ __forceinline__ float bfhi(unsigned int u) { return __uint_as_float(u & 0xffff0000u); }
__device__ __forceinline__ unsigned int packbf(float a, float b) {
  return (unsigned int)f2bf(a) | ((unsigned int)f2bf(b) << 16);
}
__device__ __forceinline__ unsigned int pkh2(float a, float b) {
  h2 v; v.x = (_Float16)a; v.y = (_Float16)b;
  return __builtin_bit_cast(unsigned int, v);
}
__device__ __forceinline__ float dot2a(h2 a, h2 b, float c) {
#if __has_builtin(__builtin_amdgcn_fdot2)
  return __builtin_amdgcn_fdot2(a, b, c, false);
#else
  return c + (float)a.x * (float)b.x + (float)a.y * (float)b.y;
#endif
}
__device__ __forceinline__ h2 ash2(unsigned int u) { return __builtin_bit_cast(h2, u); }
__device__ __forceinline__ f32x4v mfma16(uint4 a, uint4 b, f32x4v c) {
  return __builtin_amdgcn_mfma_f32_16x16x32_bf16(
      __builtin_bit_cast(bf16x8, a), __builtin_bit_cast(bf16x8, b), c, 0, 0, 0);
}

// ---------------- setup kernels ----------------

__global__ void zero_kernel(int* __restrict__ a, int* __restrict__ b,
                            float* __restrict__ bnb, int n) {
  int i = blockIdx.x * blockDim.x + threadIdx.x;
  if (i < n) { a[i] = 0; b[i] = 0; }
  if (i < 128) bnb[i] = 0.f;
}

__global__ void hist_kernel(const int* __restrict__ dst, int* __restrict__ deg, int E) {
  int e = blockIdx.x * blockDim.x + threadIdx.x;
  if (e < E) atomicAdd(&deg[dst[e]], 1);
}

__global__ void scan1_kernel(const int* __restrict__ deg, int* __restrict__ off,
                             int* __restrict__ part, int N) {
  __shared__ int sm[1024];
  int i = blockIdx.x * 1024 + threadIdx.x;
  int v = (i < N) ? deg[i] : 0;
  sm[threadIdx.x] = v;
  __syncthreads();
  for (int o = 1; o < 1024; o <<= 1) {
    int t = (threadIdx.x >= o) ? sm[threadIdx.x - o] : 0;
    __syncthreads();
    sm[threadIdx.x] += t;
    __syncthreads();
  }
  if (i < N) off[i] = sm[threadIdx.x] - v;   // exclusive
  if (threadIdx.x == 1023) part[blockIdx.x] = sm[1023];
}

__global__ void scan2_kernel(int* __restrict__ part, int* __restrict__ off, int nb, int N) {
  if (threadIdx.x == 0) {
    int run = 0;
    for (int b = 0; b < nb; b++) { int p = part[b]; part[b] = run; run += p; }
    off[N] = run;
  }
}

__global__ void scan3_kernel(int* __restrict__ off, const int* __restrict__ part, int N) {
  int i = blockIdx.x * 1024 + threadIdx.x;
  if (i < N) off[i] += part[blockIdx.x];
}

// CSR fill: scatter srcs/ews + f16-packed eattr (32B) into slot order
__global__ void fill_kernel(const int* __restrict__ src, const int* __restrict__ dst,
                            const float* __restrict__ ew, const float4* __restrict__ eattr4,
                            const int* __restrict__ off, int* __restrict__ cnt,
                            int* __restrict__ srcs, float* __restrict__ ews,
                            uint4* __restrict__ eg16, int E) {
  int e = blockIdx.x * blockDim.x + threadIdx.x;
  if (e < E) {
    int d = dst[e];
    int slot = off[d] + atomicAdd(&cnt[d], 1);
    srcs[slot] = src[e];
    ews[slot] = ew[e];
    float4 a = eattr4[e * 4 + 0], b = eattr4[e * 4 + 1];
    float4 c = eattr4[e * 4 + 2], q = eattr4[e * 4 + 3];
    uint4 u0, u1;
    u0.x = pkh2(a.x, a.y); u0.y = pkh2(a.z, a.w);
    u0.z = pkh2(b.x, b.y); u0.w = pkh2(b.z, b.w);
    u1.x = pkh2(c.x, c.y); u1.y = pkh2(c.z, c.w);
    u1.z = pkh2(q.x, q.y); u1.w = pkh2(q.z, q.w);
    eg16[(size_t)slot * 2 + 0] = u0;
    eg16[(size_t)slot * 2 + 1] = u1;
  }
}

__global__ void adl_kernel(const int* __restrict__ deg, float* __restrict__ adl, int N) {
  __shared__ float sm[1024];
  float s = 0.f;
  for (int n = threadIdx.x; n < N; n += 1024) s += logf((float)deg[n] + 1.f);
  sm[threadIdx.x] = s;
  __syncthreads();
  for (int o = 512; o > 0; o >>= 1) {
    if (threadIdx.x < o) sm[threadIdx.x] += sm[threadIdx.x + o];
    __syncthreads();
  }
  if (threadIdx.x == 0) adl[0] = sm[0];   // sum of log(deg+1); consumers divide by N
}

// h0 = x @ node_W + node_b   (x: [N,128], W: [128,32])
__global__ void node_emb_kernel(const float* __restrict__ x, const float* __restrict__ W,
                                const float* __restrict__ b, float* __restrict__ h, int N) {
  int n = blockIdx.x * 8 + (threadIdx.x >> 5);
  int j = threadIdx.x & 31;
  if (n >= N) return;
  float acc = b[j];
  const float4* x4 = (const float4*)(x + (size_t)n * 128);
#pragma unroll
  for (int q = 0; q < 32; q++) {
    float4 v = x4[q];
    acc += v.x * W[(4 * q + 0) * 32 + j];
    acc += v.y * W[(4 * q + 1) * 32 + j];
    acc += v.z * W[(4 * q + 2) * 32 + j];
    acc += v.w * W[(4 * q + 3) * 32 + j];
  }
  h[n * 32 + j] = acc;
}

// Fold edge path: Wf[l,t] = (edge_W @ enc_W[l]) @ pre_W[l,t,64:96,:]  (16x32)
__global__ void fuse_kernel(const float* __restrict__ edge_W, const float* __restrict__ edge_b,
                            const float* __restrict__ enc_W, const float* __restrict__ enc_b,
                            const float* __restrict__ pre_W, const float* __restrict__ pre_b,
                            float* __restrict__ Wf, float* __restrict__ bf) {
  __shared__ float tW[2][16][32];
  __shared__ float tb[2][32];
  int tid = threadIdx.x;
  for (int i = tid; i < 1024; i += 256) {
    int l = i >> 9, r = (i >> 5) & 15, c = i & 31;
    float s = 0.f;
    for (int k = 0; k < 32; k++) s += edge_W[r * 32 + k] * enc_W[(l * 32 + k) * 32 + c];
    tW[l][r][c] = s;
  }
  for (int i = tid; i < 64; i += 256) {
    int l = i >> 5, c = i & 31;
    float s = enc_b[l * 32 + c];
    for (int k = 0; k < 32; k++) s += edge_b[k] * enc_W[(l * 32 + k) * 32 + c];
    tb[l][c] = s;
  }
  __syncthreads();
  for (int i = tid; i < 4096; i += 256) {
    int l = i >> 11, t = (i >> 9) & 3, r = (i >> 5) & 15, c = i & 31;
    float s = 0.f;
    for (int k = 0; k < 32; k++) s += tW[l][r][k] * pre_W[((l * 4 + t) * 96 + 64 + k) * 32 + c];
    Wf[i] = s;
  }
  for (int i = tid; i < 256; i += 256) {
    int l = i >> 7, t = (i >> 5) & 3, c = i & 31;
    float s = pre_b[(l * 4 + t) * 32 + c];
    for (int k = 0; k < 32; k++) s += tb[l][k] * pre_W[((l * 4 + t) * 96 + 64 + k) * 32 + c];
    bf[i] = s;
  }
}

// ---------------- fuse2: compose post_nn (block-diag) with lin -> dense B-fragments ----------------
// B[544][96] bf16, stored directly in MFMA B-fragment layout:
//   Bfrag[l][((jt*17 + ks)*64 + lane)*4 + d] = pair B[k][j], B[k+1][j]
//   with k = ks*32 + (lane>>4)*8 + 2d, j-section jsec = jt>>1 (0:m,1:amp,2:att),
//   jcol = (jt&1)*16 + (lane&15). Rows 512..543 = h block (jsec 0 only).
__global__ void fuse2_kernel(const float* __restrict__ postW_, const float* __restrict__ postB_,
                             const float* __restrict__ linW_, const float* __restrict__ linB_,
                             unsigned int* __restrict__ Bfrag, float* __restrict__ bias2) {
  int l = blockIdx.x;
  const float* postW = postW_ + (size_t)l * 13312;
  const float* postB = postB_ + l * 32;
  const float* linW = linW_ + l * 1024;
  const float* linB = linB_ + l * 32;
  unsigned int* Bf = Bfrag + (size_t)l * 26112;
  int tid = threadIdx.x;
  for (int idx = tid; idx < 26112; idx += 256) {
    int d = idx & 3, lane = (idx >> 2) & 63;
    int ks = (idx >> 8) % 17, jt = (idx >> 8) / 17;
    int jcol = (jt & 1) * 16 + (lane & 15);
    int jsec = jt >> 1;
    float v[2];
#pragma unroll
    for (int e2 = 0; e2 < 2; ++e2) {
      int k = ks * 32 + ((lane >> 4) << 3) + 2 * d + e2;
      float s = 0.f;
      if (k < 512) {
        int st = k >> 7, t = (k >> 5) & 3, g = k & 31;
        int rowW = 32 + jsec * 128 + st * 32 + g;
        for (int q = 0; q < 8; ++q)
          s += postW[t * 3328 + rowW * 8 + q] * linW[(t * 8 + q) * 32 + jcol];
      } else if (jsec == 0) {
        int kk = k - 512;
        for (int c = 0; c < 32; ++c)
          s += postW[(c >> 3) * 3328 + kk * 8 + (c & 7)] * linW[c * 32 + jcol];
      }
      v[e2] = s;
    }
    Bf[idx] = packbf(v[0], v[1]);
  }
  if (tid < 32) {
    float s = linB[tid];
    for (int c = 0; c < 32; ++c) s += postB[c] * linW[c * 32 + tid];
    bias2[l * 32 + tid] = s;
  }
}

// ---------------- per-layer: node pre-projection (+ hB fragment) ----------------
__global__ __launch_bounds__(256) void prep_kernel(
    const float* __restrict__ h, const float* __restrict__ preW,
    const float* __restrict__ bfv, unsigned short* __restrict__ qB,
    unsigned short* __restrict__ AB, unsigned int* __restrict__ hB, int N) {
  __shared__ float hs[16][32];
  int tid = threadIdx.x;
  int c = tid & 127, half = tid >> 7;
  int t = c >> 5, g = c & 31;
  float ws[32], wd[32];
  {
    const float* pS = preW + (t * 96 + 32) * 32 + g;
    const float* pD = preW + (t * 96) * 32 + g;
#pragma unroll
    for (int k = 0; k < 32; k++) { ws[k] = pS[k * 32]; wd[k] = pD[k * 32]; }
  }
  float bc = bfv[c];
  int base = blockIdx.x * 16;
  for (int i = tid; i < 512; i += 256) {
    int nn = i >> 5;
    hs[nn][i & 31] = (base + nn < N) ? h[(size_t)(base + nn) * 32 + (i & 31)] : 0.f;
  }
  __syncthreads();
  {
    int nn = tid >> 4, w = tid & 15;
    int n = base + nn;
    if (n < N) hB[(size_t)n * 16 + w] = packbf(hs[nn][2 * w], hs[nn][2 * w + 1]);
  }
#pragma unroll
  for (int nn = 0; nn < 8; ++nn) {
    int nl = half + 2 * nn;
    int n = base + nl;
    if (n >= N) continue;
    float qa = 0.f, Aa = bc;
#pragma unroll
    for (int k = 0; k < 32; k++) {
      float hk = hs[nl][k];
      qa = fmaf(hk, ws[k], qa);
      Aa = fmaf(hk, wd[k], Aa);
    }
    qB[(size_t)n * 128 + c] = f2bf(qa);
    AB[(size_t)n * 128 + c] = f2bf(Aa);
  }
}

// ---------------- fused BN-apply + next-layer pre-projection (+ hB) ----------------
__global__ __launch_bounds__(256) void bnprep_kernel(
    const float* __restrict__ pre, const float* __restrict__ bnv,
    const float* __restrict__ gamma, const float* __restrict__ beta,
    const float* __restrict__ preW, const float* __restrict__ bfv,
    float* __restrict__ h, unsigned short* __restrict__ qB,
    unsigned short* __restrict__ AB, unsigned int* __restrict__ hB, int N) {
  __shared__ float hs[16][32];
  int tid = threadIdx.x;
  int base = blockIdx.x * 16;
  float invN = 1.f / (float)N;
  for (int idx = tid; idx < 512; idx += 256) {
    int nn = idx >> 5, j = idx & 31;
    int n = base + nn;
    float v = 0.f;
    if (n < N) {
      float mu = bnv[j] * invN;
      float var = bnv[32 + j] * invN - mu * mu;
      float is = rsqrtf(var + kEps);
      v = fmaxf((pre[(size_t)n * 32 + j] - mu) * is * gamma[j] + beta[j], 0.f);
      h[(size_t)n * 32 + j] = v;
    }
    hs[nn][j] = v;
  }
  int c = tid & 127, half = tid >> 7;
  int t = c >> 5, g = c & 31;
  float ws[32], wd[32];
  {
    const float* pS = preW + (t * 96 + 32) * 32 + g;
    const float* pD = preW + (t * 96) * 32 + g;
#pragma unroll
    for (int k = 0; k < 32; k++) { ws[k] = pS[k * 32]; wd[k] = pD[k * 32]; }
  }
  float bc = bfv[c];
  __syncthreads();
  {
    int nn = tid >> 4, w = tid & 15;
    int n = base + nn;
    if (n < N) hB[(size_t)n * 16 + w] = packbf(hs[nn][2 * w], hs[nn][2 * w + 1]);
  }
#pragma unroll
  for (int nn = 0; nn < 8; ++nn) {
    int nl = half + 2 * nn;
    int n = base + nl;
    if (n >= N) continue;
    float qa = 0.f, Aa = bc;
#pragma unroll
    for (int k = 0; k < 32; k++) {
      float hk = hs[nl][k];
      qa = fmaf(hk, ws[k], qa);
      Aa = fmaf(hk, wd[k], Aa);
    }
    qB[(size_t)n * 128 + c] = f2bf(qa);
    AB[(size_t)n * 128 + c] = f2bf(Aa);
  }
}

// ---------------- per-layer: fused aggregation (proven R13 structure) ----------------
#define DOTE(F0, F1, UA, UB)                                         \
  F0 = dot2a(ash2(UA.x), w0[0], F0); F1 = dot2a(ash2(UA.x), w1[0], F1); \
  F0 = dot2a(ash2(UA.y), w0[1], F0); F1 = dot2a(ash2(UA.y), w1[1], F1); \
  F0 = dot2a(ash2(UA.z), w0[2], F0); F1 = dot2a(ash2(UA.z), w1[2], F1); \
  F0 = dot2a(ash2(UA.w), w0[3], F0); F1 = dot2a(ash2(UA.w), w1[3], F1); \
  F0 = dot2a(ash2(UB.x), w0[4], F0); F1 = dot2a(ash2(UB.x), w1[4], F1); \
  F0 = dot2a(ash2(UB.y), w0[5], F0); F1 = dot2a(ash2(UB.y), w1[5], F1); \
  F0 = dot2a(ash2(UB.z), w0[6], F0); F1 = dot2a(ash2(UB.z), w1[6], F1); \
  F0 = dot2a(ash2(UB.w), w0[7], F0); F1 = dot2a(ash2(UB.w), w1[7], F1);

#define STATACC(V0, V1)                                                    \
  s0a += V0; sq0 = fmaf(V0, V0, sq0); mn0 = fminf(mn0, V0); mx0 = fmaxf(mx0, V0); \
  s1a += V1; sq1 = fmaf(V1, V1, sq1); mn1 = fminf(mn1, V1); mx1 = fmaxf(mx1, V1);

__global__ __launch_bounds__(256, 4) void agg10b_kernel(
    const unsigned int* __restrict__ qB, const unsigned int* __restrict__ AB,
    const int* __restrict__ coff, const int* __restrict__ srcs,
    const float* __restrict__ ews, const uint4* __restrict__ eg16,
    const float* __restrict__ Wf, unsigned int* __restrict__ stats, int N) {
  int lane = threadIdx.x & 63;
  int wv = (blockIdx.x * blockDim.x + threadIdx.x) >> 6;
  int nwaves = (gridDim.x * blockDim.x) >> 6;
  int t = lane >> 4, g0 = (2 * lane) & 31;
  h2 w0[8], w1[8];
  {
    const float* p = Wf + t * 512 + g0;
#pragma unroll
    for (int k = 0; k < 8; k++) {
      w0[k].x = (_Float16)p[(2 * k) * 32];     w0[k].y = (_Float16)p[(2 * k + 1) * 32];
      w1[k].x = (_Float16)p[(2 * k) * 32 + 1]; w1[k].y = (_Float16)p[(2 * k + 1) * 32 + 1];
    }
  }
  for (int n = wv; n < N; n += nwaves) {
    unsigned int au = AB[(size_t)n * 64 + lane];
    float a0 = bflo(au), a1 = bfhi(au);
    int beg = coff[n], end = coff[n + 1];
    int dg = end - beg;
    float s0a = 0.f, s1a = 0.f, sq0 = 0.f, sq1 = 0.f;
    float mn0 = 1e30f, mn1 = 1e30f, mx0 = -1e30f, mx1 = -1e30f;

    int i = beg;
    unsigned int q0 = 0, q1 = 0, q2 = 0, q3 = 0;
    int sc0 = 0, sc1 = 0, sc2 = 0, sc3 = 0;
    if (i + 4 <= end) {
      int t0 = srcs[i], t1 = srcs[i + 1], t2 = srcs[i + 2], t3 = srcs[i + 3];
      q0 = qB[(size_t)t0 * 64 + lane];
      q1 = qB[(size_t)t1 * 64 + lane];
      q2 = qB[(size_t)t2 * 64 + lane];
      q3 = qB[(size_t)t3 * 64 + lane];
    }
    if (i + 8 <= end) { sc0 = srcs[i + 4]; sc1 = srcs[i + 5]; sc2 = srcs[i + 6]; sc3 = srcs[i + 7]; }
    for (; i + 4 <= end; i += 4) {
      unsigned int nq0 = 0, nq1 = 0, nq2 = 0, nq3 = 0;
      if (i + 8 <= end) {
        nq0 = qB[(size_t)sc0 * 64 + lane];
        nq1 = qB[(size_t)sc1 * 64 + lane];
        nq2 = qB[(size_t)sc2 * 64 + lane];
        nq3 = qB[(size_t)sc3 * 64 + lane];
      }
      float w0s = ews[i], w1s = ews[i + 1], w2s = ews[i + 2], w3s = ews[i + 3];
      const uint4* ep = eg16 + (size_t)i * 2;
      uint4 eA0 = ep[0], eA1 = ep[1], eB0 = ep[2], eB1 = ep[3];
      uint4 eC0 = ep[4], eC1 = ep[5], eD0 = ep[6], eD1 = ep[7];
      if (i + 12 <= end) { sc0 = srcs[i + 8]; sc1 = srcs[i + 9]; sc2 = srcs[i + 10]; sc3 = srcs[i + 11]; }
      float f00 = 0.f, f10 = 0.f, f01 = 0.f, f11 = 0.f;
      float f02 = 0.f, f12 = 0.f, f03 = 0.f, f13 = 0.f;
      DOTE(f00, f10, eA0, eA1)
      DOTE(f01, f11, eB0, eB1)
      DOTE(f02, f12, eC0, eC1)
      DOTE(f03, f13, eD0, eD1)
      float v0, v1;
      v0 = (a0 + bflo(q0) + f00) * w0s; v1 = (a1 + bfhi(q0) + f10) * w0s; STATACC(v0, v1)
      v0 = (a0 + bflo(q1) + f01) * w1s; v1 = (a1 + bfhi(q1) + f11) * w1s; STATACC(v0, v1)
      v0 = (a0 + bflo(q2) + f02) * w2s; v1 = (a1 + bfhi(q2) + f12) * w2s; STATACC(v0, v1)
      v0 = (a0 + bflo(q3) + f03) * w3s; v1 = (a1 + bfhi(q3) + f13) * w3s; STATACC(v0, v1)
      q0 = nq0; q1 = nq1; q2 = nq2; q3 = nq3;
    }
    for (; i < end; ++i) {
      int s = srcs[i];
      unsigned int q = qB[(size_t)s * 64 + lane];
      float w = ews[i];
      const uint4* ep = eg16 + (size_t)i * 2;
      uint4 ea = ep[0], eb = ep[1];
      float f0 = 0.f, f1 = 0.f;
      DOTE(f0, f1, ea, eb)
      float v0 = (a0 + bflo(q) + f0) * w;
      float v1 = (a1 + bfhi(q) + f1) * w;
      STATACC(v0, v1)
    }
    if (dg == 0) { mn0 = 0.f; mx0 = 0.f; mn1 = 0.f; mx1 = 0.f; }
    float inv = 1.f / (float)(dg > 0 ? dg : 1);
    float mean0 = s0a * inv, mean1 = s1a * inv;
    float sd0 = sqrtf(fmaxf(sq0 * inv - mean0 * mean0, 0.f) + kEps);
    float sd1 = sqrtf(fmaxf(sq1 * inv - mean1 * mean1, 0.f) + kEps);
    unsigned int* sp = stats + (size_t)n * 256;
    sp[0 * 64 + lane] = packbf(mean0, mean1);
    sp[1 * 64 + lane] = packbf(mn0, mn1);
    sp[2 * 64 + lane] = packbf(mx0, mx1);
    sp[3 * 64 + lane] = packbf(sd0, sd1);
  }
}

// ---------------- per-layer: MFMA post (S|h @ composed weights) + BN partials ----------------
// Wave = 16-node tile; 6 j-tiles x 17 k-steps of mfma_f32_16x16x32_bf16.
// A-frags read directly from stats/hB (index algebra matches lane layout).
// B staged in LDS in 3 stages (6/6/5 k-steps) to cut global B traffic.
__global__ __launch_bounds__(256) void postm_kernel(
    const uint4* __restrict__ statsU4, const uint4* __restrict__ hBU4,
    const int* __restrict__ coff, const float* __restrict__ adl,
    const unsigned int* __restrict__ BfragL, const float* __restrict__ bias2,
    float* __restrict__ pre, float* __restrict__ bn, int N, int ntcnt) {
  __shared__ uint4 Bs[6 * 6 * 64];   // 36 KB
  int tid = threadIdx.x, wave = tid >> 6, lane = tid & 63;
  int nt = blockIdx.x * 4 + wave;
  int ntb = nt * 16;
  int ntbC = (nt < ntcnt ? nt : ntcnt - 1) * 16;   // clamped for loads only
  const uint4* Bf4 = (const uint4*)BfragL;

  f32x4v acc[6];
#pragma unroll
  for (int jt = 0; jt < 6; ++jt) { acc[jt].x = 0.f; acc[jt].y = 0.f; acc[jt].z = 0.f; acc[jt].w = 0.f; }

  int ksBase = 0;
  for (int stage = 0; stage < 3; ++stage) {
    int ksN = (stage == 2) ? 5 : 6;
    for (int i = tid; i < 6 * ksN * 64; i += 256) {
      int ln = i & 63, rest = i >> 6;
      int ksl = rest % ksN, jt = rest / ksN;
      Bs[(jt * 6 + ksl) * 64 + ln] = Bf4[(jt * 17 + ksBase + ksl) * 64 + ln];
    }
    __syncthreads();
    for (int ksl = 0; ksl < ksN; ++ksl) {
      int ks = ksBase + ksl;
      uint4 a;
      if (ks < 16) {
        a = statsU4[(size_t)(ntbC + (lane & 15)) * 64 + (ks >> 2) * 16 + (ks & 3) * 4 + (lane >> 4)];
      } else {
        a = hBU4[(size_t)(ntbC + (lane & 15)) * 4 + (lane >> 4)];
      }
#pragma unroll
      for (int jt = 0; jt < 6; ++jt)
        acc[jt] = mfma16(a, Bs[(jt * 6 + ksl) * 64 + lane], acc[jt]);
    }
    __syncthreads();
    ksBase += ksN;
  }

  // epilogue: D layout col=lane&15, row=(lane>>4)*4+reg
  float adv = adl[0] / (float)N;
  int j0 = lane & 15;
  float bs0 = 0.f, bq0 = 0.f, bs1 = 0.f, bq1 = 0.f;
#pragma unroll
  for (int reg = 0; reg < 4; ++reg) {
    int n = ntb + ((lane >> 4) << 2) + reg;
    if (n < N) {
      int dg = coff[n + 1] - coff[n];
      float degc = (float)(dg > 0 ? dg : 1);
      float ld = logf(degc + 1.f);
      float amp = ld / adv, att = adv / ld;
      float v0 = bias2[j0]      + acc[0][reg] + amp * acc[2][reg] + att * acc[4][reg];
      float v1 = bias2[16 + j0] + acc[1][reg] + amp * acc[3][reg] + att * acc[5][reg];
      pre[(size_t)n * 32 + j0] = v0;
      pre[(size_t)n * 32 + 16 + j0] = v1;
      bs0 += v0; bq0 = fmaf(v0, v0, bq0);
      bs1 += v1; bq1 = fmaf(v1, v1, bq1);
    }
  }
  bs0 += __shfl_xor(bs0, 16); bs0 += __shfl_xor(bs0, 32);
  bq0 += __shfl_xor(bq0, 16); bq0 += __shfl_xor(bq0, 32);
  bs1 += __shfl_xor(bs1, 16); bs1 += __shfl_xor(bs1, 32);
  bq1 += __shfl_xor(bq1, 16); bq1 += __shfl_xor(bq1, 32);
  if (lane < 16) {
    atomicAdd(&bn[j0], bs0);
    atomicAdd(&bn[32 + j0], bq0);
    atomicAdd(&bn[16 + j0], bs1);
    atomicAdd(&bn[48 + j0], bq1);
  }
}

// ---------------- fused BN-apply + pooling, then MLP ----------------

__device__ __forceinline__ int lower_bound_dev(const int* a, int n, int key) {
  int lo = 0, hi = n;
  while (lo < hi) {
    int m = (lo + hi) >> 1;
    if (a[m] < key) lo = m + 1; else hi = m;
  }
  return lo;
}

__global__ void pool2_kernel(const float* __restrict__ pre, const float* __restrict__ bnv,
                             const float* __restrict__ gamma, const float* __restrict__ beta,
                             const int* __restrict__ batch, float* __restrict__ gp, int N) {
  int gi = blockIdx.x;  // 64 graphs
  int lo = lower_bound_dev(batch, N, gi);
  int hi = lower_bound_dev(batch, N, gi + 1);
  __shared__ float part[8][32];
  int j = threadIdx.x & 31, ch = threadIdx.x >> 5;
  float invN = 1.f / (float)N;
  float mu = bnv[j] * invN;
  float var = bnv[32 + j] * invN - mu * mu;
  float is = rsqrtf(var + kEps);
  float gm = gamma[j], bt = beta[j];
  float s = 0.f;
  for (int n = lo + ch; n < hi; n += 8)
    s += fmaxf((pre[(size_t)n * 32 + j] - mu) * is * gm + bt, 0.f);
  part[ch][j] = s;
  __syncthreads();
  if (threadIdx.x < 32) {
    float t = 0.f;
    for (int c2 = 0; c2 < 8; c2++) t += part[c2][j];
    gp[gi * 32 + j] = t;
  }
}

__global__ void mlp_kernel(const float* __restrict__ gp,
                           const float* __restrict__ W1, const float* __restrict__ b1,
                           const float* __restrict__ W2, const float* __restrict__ b2,
                           const float* __restrict__ W3, const float* __restrict__ b3,
                           float* __restrict__ out) {
  __shared__ float g1[64 * 32];
  __shared__ float g2[64 * 16];
  int tid = threadIdx.x;  // 256
  for (int i = tid; i < 2048; i += 256) {
    int r = i >> 5, c = i & 31;
    float s = b1[c];
    for (int k = 0; k < 32; k++) s += gp[r * 32 + k] * W1[k * 32 + c];
    g1[i] = fmaxf(s, 0.f);
  }
  __syncthreads();
  for (int i = tid; i < 1024; i += 256) {
    int r = i >> 4, c = i & 15;
    float s = b2[c];
    for (int k = 0; k < 32; k++) s += g1[r * 32 + k] * W2[k * 16 + c];
    g2[i] = fmaxf(s, 0.f);
  }
  __syncthreads();
  if (tid < 64) {
    float s = b3[0];
    for (int k = 0; k < 16; k++) s += g2[tid * 16 + k] * W3[k];
    out[tid] = s;
  }
}

// ---------------- launch ----------------

extern "C" void kernel_launch(void* const* d_in, const int* in_sizes, int n_in,
                              void* d_out, int out_size, void* d_ws, size_t ws_size,
                              hipStream_t stream) {
  (void)n_in; (void)out_size; (void)ws_size;
  const float* x     = (const float*)d_in[0];
  const float* eattr = (const float*)d_in[1];
  const float* ew    = (const float*)d_in[2];
  const int*   eidx  = (const int*)d_in[3];
  const int*   batch = (const int*)d_in[4];
  const float* nodeW = (const float*)d_in[5];
  const float* nodeB = (const float*)d_in[6];
  const float* edgeW = (const float*)d_in[7];
  const float* edgeB = (const float*)d_in[8];
  const float* encW  = (const float*)d_in[9];
  const float* encB  = (const float*)d_in[10];
  const float* preW  = (const float*)d_in[11];
  const float* preB  = (const float*)d_in[12];
  const float* postW = (const float*)d_in[13];
  const float* postB = (const float*)d_in[14];
  const float* linW  = (const float*)d_in[15];
  const float* linB  = (const float*)d_in[16];
  const float* bnG   = (const float*)d_in[17];
  const float* bnB   = (const float*)d_in[18];
  const float* W1    = (const float*)d_in[19];
  const float* b1    = (const float*)d_in[20];
  const float* W2    = (const float*)d_in[21];
  const float* b2    = (const float*)d_in[22];
  const float* W3    = (const float*)d_in[23];
  const float* b3    = (const float*)d_in[24];
  float* out = (float*)d_out;

  int N = in_sizes[0] / 128;
  int E = in_sizes[2];
  const int* srcp = eidx;
  const int* dstp = eidx + E;

  char* wsb = (char*)d_ws;
  size_t woff = 0;
  auto alloc = [&](size_t bytes) -> void* {
    void* p = (void*)(wsb + woff);
    woff += (bytes + 255) & ~(size_t)255;
    return p;
  };
  int* deg   = (int*)alloc((size_t)N * 4);
  int* cnt   = (int*)alloc((size_t)N * 4);
  int* coff  = (int*)alloc((size_t)(N + 1) * 4);
  int* part  = (int*)alloc(64 * 4);
  int* srcs  = (int*)alloc((size_t)E * 4);
  float* ews = (float*)alloc((size_t)E * 4);
  unsigned int* eg16 = (unsigned int*)alloc((size_t)E * 32);
  float* h    = (float*)alloc((size_t)N * 32 * 4);
  float* pre  = (float*)alloc((size_t)N * 32 * 4);
  float* adl  = (float*)alloc(256);
  float* bnbuf = (float*)alloc(2 * 64 * 4);
  float* gp   = (float*)alloc(64 * 32 * 4);
  float* WfB  = (float*)alloc(2 * 4 * 16 * 32 * 4);
  float* bfB  = (float*)alloc(2 * 4 * 32 * 4);
  unsigned short* qB  = (unsigned short*)alloc((size_t)N * 128 * 2);
  unsigned short* AB  = (unsigned short*)alloc((size_t)N * 128 * 2);
  unsigned int* stats = (unsigned int*)alloc((size_t)(N + 16) * 256 * 4);  // padded tile
  unsigned int* hB    = (unsigned int*)alloc((size_t)(N + 16) * 16 * 4);   // bf16 h frags
  unsigned int* Bfrag = (unsigned int*)alloc(2 * 26112 * 4);
  float* bias2 = (float*)alloc(2 * 32 * 4);

  int nb = (N + 1023) / 1024;
  int ntcnt = (N + 15) / 16;
  int grid_pm = (ntcnt + 3) / 4;

  zero_kernel<<<(N + 255) / 256, 256, 0, stream>>>(deg, cnt, bnbuf, N);
  hist_kernel<<<(E + 255) / 256, 256, 0, stream>>>(dstp, deg, E);
  scan1_kernel<<<nb, 1024, 0, stream>>>(deg, coff, part, N);
  scan2_kernel<<<1, 64, 0, stream>>>(part, coff, nb, N);
  scan3_kernel<<<nb, 1024, 0, stream>>>(coff, part, N);
  fill_kernel<<<(E + 255) / 256, 256, 0, stream>>>(srcp, dstp, ew, (const float4*)eattr,
                                                   coff, cnt, srcs, ews, (uint4*)eg16, E);
  adl_kernel<<<1, 1024, 0, stream>>>(deg, adl, N);
  node_emb_kernel<<<(N + 7) / 8, 256, 0, stream>>>(x, nodeW, nodeB, h, N);
  fuse_kernel<<<1, 256, 0, stream>>>(edgeW, edgeB, encW, encB, preW, preB, WfB, bfB);
  fuse2_kernel<<<2, 256, 0, stream>>>(postW, postB, linW, linB, Bfrag, bias2);

  // layer 0
  prep_kernel<<<(N + 15) / 16, 256, 0, stream>>>(h, preW, bfB, qB, AB, hB, N);
  agg10b_kernel<<<2048, 256, 0, stream>>>(
      (const unsigned int*)qB, (const unsigned int*)AB, coff, srcs, ews,
      (const uint4*)eg16, WfB, stats, N);
  postm_kernel<<<grid_pm, 256, 0, stream>>>(
      (const uint4*)stats, (const uint4*)hB, coff, adl, Bfrag, bias2,
      pre, bnbuf, N, ntcnt);
  // fused bn_apply(l0) + prep(l1)
  bnprep_kernel<<<(N + 15) / 16, 256, 0, stream>>>(
      pre, bnbuf, bnG, bnB, preW + 12288, bfB + 128, h, qB, AB, hB, N);
  // layer 1
  agg10b_kernel<<<2048, 256, 0, stream>>>(
      (const unsigned int*)qB, (const unsigned int*)AB, coff, srcs, ews,
      (const uint4*)eg16, WfB + 2048, stats, N);
  postm_kernel<<<grid_pm, 256, 0, stream>>>(
      (const uint4*)stats, (const uint4*)hB, coff, adl, Bfrag + 26112, bias2 + 32,
      pre, bnbuf + 64, N, ntcnt);
  // fused bn_apply(l1) + pooling
  pool2_kernel<<<64, 256, 0, stream>>>(pre, bnbuf + 64, bnG + 32, bnB + 32, batch, gp, N);
  mlp_kernel<<<1, 256, 0, stream>>>(gp, W1, b1, W2, b2, W3, b3, out);
}

// Round 15
// 387.538 us; speedup vs baseline: 1.2587x; 1.2587x over previous
//
#include <hip/hip_runtime.h>

constexpr float kEps = 1e-5f;

typedef _Float16 h2 __attribute__((ext_vector_type(2)));
typedef float f2v __attribute__((ext_vector_type(2)));
typedef short bf16x8 __attribute__((ext_vector_type(8)));
typedef float f32x4v __attribute__((ext_vector_type(4)));

__device__ __forceinline__ unsigned short f2bf(float x) {
  unsigned int u = __float_as_uint(x);
  unsigned int r = (u + 0x7fffu + ((u >> 16) & 1u)) >> 16;
  return (unsigned short)r;
}
__device__ __forceinline__ float bflo(unsigned int u) { return __uint_as_float(u << 16); }
__device__ __forceinline__ float bfhi(unsigned int u) { return __uint_as_float(u & 0xffff0000u); }
__device__ __forceinline__ unsigned int packbf(float a, float b) {
  return (unsigned int)f2bf(a) | ((unsigned int)f2bf(b) << 16);
}
__device__ __forceinline__ unsigned int pkh2(float a, float b) {
  h2 v; v.x = (_Float16)a; v.y = (_Float16)b;
  return __builtin_bit_cast(unsigned int, v);
}
__device__ __forceinline__ float dot2a(h2 a, h2 b, float c) {
#if __has_builtin(__builtin_amdgcn_fdot2)
  return __builtin_amdgcn_fdot2(a, b, c, false);
#else
  return c + (float)a.x * (float)b.x + (float)a.y * (float)b.y;
#endif
}
__device__ __forceinline__ h2 ash2(unsigned int u) { return __builtin_bit_cast(h2, u); }
__device__ __forceinline__ f32x4v mfma16(uint4 a, uint4 b, f32x4v c) {
  return __builtin_amdgcn_mfma_f32_16x16x32_bf16(
      __builtin_bit_cast(bf16x8, a), __builtin_bit_cast(bf16x8, b), c, 0, 0, 0);
}

// ---------------- setup kernels ----------------

__global__ void zero_kernel(int* __restrict__ a, int* __restrict__ b,
                            float* __restrict__ bnb, int n) {
  int i = blockIdx.x * blockDim.x + threadIdx.x;
  if (i < n) { a[i] = 0; b[i] = 0; }
  if (i < 128) bnb[i] = 0.f;
}

__global__ void hist_kernel(const int* __restrict__ dst, int* __restrict__ deg, int E) {
  int e = blockIdx.x * blockDim.x + threadIdx.x;
  if (e < E) atomicAdd(&deg[dst[e]], 1);
}

__global__ void scan1_kernel(const int* __restrict__ deg, int* __restrict__ off,
                             int* __restrict__ part, int N) {
  __shared__ int sm[1024];
  int i = blockIdx.x * 1024 + threadIdx.x;
  int v = (i < N) ? deg[i] : 0;
  sm[threadIdx.x] = v;
  __syncthreads();
  for (int o = 1; o < 1024; o <<= 1) {
    int t = (threadIdx.x >= o) ? sm[threadIdx.x - o] : 0;
    __syncthreads();
    sm[threadIdx.x] += t;
    __syncthreads();
  }
  if (i < N) off[i] = sm[threadIdx.x] - v;   // exclusive
  if (threadIdx.x == 1023) part[blockIdx.x] = sm[1023];
}

__global__ void scan2_kernel(int* __restrict__ part, int* __restrict__ off, int nb, int N) {
  if (threadIdx.x == 0) {
    int run = 0;
    for (int b = 0; b < nb; b++) { int p = part[b]; part[b] = run; run += p; }
    off[N] = run;
  }
}

__global__ void scan3_kernel(int* __restrict__ off, const int* __restrict__ part, int N) {
  int i = blockIdx.x * 1024 + threadIdx.x;
  if (i < N) off[i] += part[blockIdx.x];
}

// CSR fill: scatter srcs/ews + f16-packed eattr (32B) into slot order
__global__ void fill_kernel(const int* __restrict__ src, const int* __restrict__ dst,
                            const float* __restrict__ ew, const float4* __restrict__ eattr4,
                            const int* __restrict__ off, int* __restrict__ cnt,
                            int* __restrict__ srcs, float* __restrict__ ews,
                            uint4* __restrict__ eg16, int E) {
  int e = blockIdx.x * blockDim.x + threadIdx.x;
  if (e < E) {
    int d = dst[e];
    int slot = off[d] + atomicAdd(&cnt[d], 1);
    srcs[slot] = src[e];
    ews[slot] = ew[e];
    float4 a = eattr4[e * 4 + 0], b = eattr4[e * 4 + 1];
    float4 c = eattr4[e * 4 + 2], q = eattr4[e * 4 + 3];
    uint4 u0, u1;
    u0.x = pkh2(a.x, a.y); u0.y = pkh2(a.z, a.w);
    u0.z = pkh2(b.x, b.y); u0.w = pkh2(b.z, b.w);
    u1.x = pkh2(c.x, c.y); u1.y = pkh2(c.z, c.w);
    u1.z = pkh2(q.x, q.y); u1.w = pkh2(q.z, q.w);
    eg16[(size_t)slot * 2 + 0] = u0;
    eg16[(size_t)slot * 2 + 1] = u1;
  }
}

__global__ void adl_kernel(const int* __restrict__ deg, float* __restrict__ adl, int N) {
  __shared__ float sm[1024];
  float s = 0.f;
  for (int n = threadIdx.x; n < N; n += 1024) s += logf((float)deg[n] + 1.f);
  sm[threadIdx.x] = s;
  __syncthreads();
  for (int o = 512; o > 0; o >>= 1) {
    if (threadIdx.x < o) sm[threadIdx.x] += sm[threadIdx.x + o];
    __syncthreads();
  }
  if (threadIdx.x == 0) adl[0] = sm[0];   // sum of log(deg+1); consumers divide by N
}

// h0 = x @ node_W + node_b   (x: [N,128], W: [128,32])
__global__ void node_emb_kernel(const float* __restrict__ x, const float* __restrict__ W,
                                const float* __restrict__ b, float* __restrict__ h, int N) {
  int n = blockIdx.x * 8 + (threadIdx.x >> 5);
  int j = threadIdx.x & 31;
  if (n >= N) return;
  float acc = b[j];
  const float4* x4 = (const float4*)(x + (size_t)n * 128);
#pragma unroll
  for (int q = 0; q < 32; q++) {
    float4 v = x4[q];
    acc += v.x * W[(4 * q + 0) * 32 + j];
    acc += v.y * W[(4 * q + 1) * 32 + j];
    acc += v.z * W[(4 * q + 2) * 32 + j];
    acc += v.w * W[(4 * q + 3) * 32 + j];
  }
  h[n * 32 + j] = acc;
}

// Fold edge path: Wf[l,t] = (edge_W @ enc_W[l]) @ pre_W[l,t,64:96,:]  (16x32)
__global__ void fuse_kernel(const float* __restrict__ edge_W, const float* __restrict__ edge_b,
                            const float* __restrict__ enc_W, const float* __restrict__ enc_b,
                            const float* __restrict__ pre_W, const float* __restrict__ pre_b,
                            float* __restrict__ Wf, float* __restrict__ bf) {
  __shared__ float tW[2][16][32];
  __shared__ float tb[2][32];
  int tid = threadIdx.x;
  for (int i = tid; i < 1024; i += 256) {
    int l = i >> 9, r = (i >> 5) & 15, c = i & 31;
    float s = 0.f;
    for (int k = 0; k < 32; k++) s += edge_W[r * 32 + k] * enc_W[(l * 32 + k) * 32 + c];
    tW[l][r][c] = s;
  }
  for (int i = tid; i < 64; i += 256) {
    int l = i >> 5, c = i & 31;
    float s = enc_b[l * 32 + c];
    for (int k = 0; k < 32; k++) s += edge_b[k] * enc_W[(l * 32 + k) * 32 + c];
    tb[l][c] = s;
  }
  __syncthreads();
  for (int i = tid; i < 4096; i += 256) {
    int l = i >> 11, t = (i >> 9) & 3, r = (i >> 5) & 15, c = i & 31;
    float s = 0.f;
    for (int k = 0; k < 32; k++) s += tW[l][r][k] * pre_W[((l * 4 + t) * 96 + 64 + k) * 32 + c];
    Wf[i] = s;
  }
  for (int i = tid; i < 256; i += 256) {
    int l = i >> 7, t = (i >> 5) & 3, c = i & 31;
    float s = pre_b[(l * 4 + t) * 32 + c];
    for (int k = 0; k < 32; k++) s += tb[l][k] * pre_W[((l * 4 + t) * 96 + 64 + k) * 32 + c];
    bf[i] = s;
  }
}

// ---------------- fuse2: compose post_nn (block-diag) with lin -> dense B-fragments ----------------
// Parallel: one entry per thread across 2*26112 entries (+64 bias entries).
__global__ void fuse2_kernel(const float* __restrict__ postW_, const float* __restrict__ postB_,
                             const float* __restrict__ linW_, const float* __restrict__ linB_,
                             unsigned int* __restrict__ Bfrag, float* __restrict__ bias2) {
  int gidx = blockIdx.x * blockDim.x + threadIdx.x;
  if (gidx < 2 * 26112) {
    int l = gidx / 26112, idx = gidx % 26112;
    const float* postW = postW_ + (size_t)l * 13312;
    const float* linW = linW_ + l * 1024;
    int d = idx & 3, lane = (idx >> 2) & 63;
    int ks = (idx >> 8) % 17, jt = (idx >> 8) / 17;
    int jcol = (jt & 1) * 16 + (lane & 15);
    int jsec = jt >> 1;
    float v[2];
#pragma unroll
    for (int e2 = 0; e2 < 2; ++e2) {
      int k = ks * 32 + ((lane >> 4) << 3) + 2 * d + e2;
      float s = 0.f;
      if (k < 512) {
        int st = k >> 7, t = (k >> 5) & 3, g = k & 31;
        int rowW = 32 + jsec * 128 + st * 32 + g;
        for (int q = 0; q < 8; ++q)
          s += postW[t * 3328 + rowW * 8 + q] * linW[(t * 8 + q) * 32 + jcol];
      } else if (jsec == 0) {
        int kk = k - 512;
        for (int c = 0; c < 32; ++c)
          s += postW[(c >> 3) * 3328 + kk * 8 + (c & 7)] * linW[c * 32 + jcol];
      }
      v[e2] = s;
    }
    Bfrag[(size_t)l * 26112 + idx] = packbf(v[0], v[1]);
  }
  if (gidx < 64) {
    int l = gidx >> 5, j = gidx & 31;
    const float* postB = postB_ + l * 32;
    const float* linW = linW_ + l * 1024;
    float s = linB_[l * 32 + j];
    for (int c = 0; c < 32; ++c) s += postB[c] * linW[c * 32 + j];
    bias2[l * 32 + j] = s;
  }
}

// ---------------- per-layer: node pre-projection (+ hB fragment) ----------------
__global__ __launch_bounds__(256) void prep_kernel(
    const float* __restrict__ h, const float* __restrict__ preW,
    const float* __restrict__ bfv, unsigned short* __restrict__ qB,
    unsigned short* __restrict__ AB, unsigned int* __restrict__ hB, int N) {
  __shared__ float hs[16][32];
  int tid = threadIdx.x;
  int c = tid & 127, half = tid >> 7;
  int t = c >> 5, g = c & 31;
  float ws[32], wd[32];
  {
    const float* pS = preW + (t * 96 + 32) * 32 + g;
    const float* pD = preW + (t * 96) * 32 + g;
#pragma unroll
    for (int k = 0; k < 32; k++) { ws[k] = pS[k * 32]; wd[k] = pD[k * 32]; }
  }
  float bc = bfv[c];
  int base = blockIdx.x * 16;
  for (int i = tid; i < 512; i += 256) {
    int nn = i >> 5;
    hs[nn][i & 31] = (base + nn < N) ? h[(size_t)(base + nn) * 32 + (i & 31)] : 0.f;
  }
  __syncthreads();
  {
    int nn = tid >> 4, w = tid & 15;
    int n = base + nn;
    if (n < N) hB[(size_t)n * 16 + w] = packbf(hs[nn][2 * w], hs[nn][2 * w + 1]);
  }
#pragma unroll
  for (int nn = 0; nn < 8; ++nn) {
    int nl = half + 2 * nn;
    int n = base + nl;
    if (n >= N) continue;
    float qa = 0.f, Aa = bc;
#pragma unroll
    for (int k = 0; k < 32; k++) {
      float hk = hs[nl][k];
      qa = fmaf(hk, ws[k], qa);
      Aa = fmaf(hk, wd[k], Aa);
    }
    qB[(size_t)n * 128 + c] = f2bf(qa);
    AB[(size_t)n * 128 + c] = f2bf(Aa);
  }
}

// ---------------- fused BN-apply + next-layer pre-projection (+ hB) ----------------
__global__ __launch_bounds__(256) void bnprep_kernel(
    const float* __restrict__ pre, const float* __restrict__ bnv,
    const float* __restrict__ gamma, const float* __restrict__ beta,
    const float* __restrict__ preW, const float* __restrict__ bfv,
    float* __restrict__ h, unsigned short* __restrict__ qB,
    unsigned short* __restrict__ AB, unsigned int* __restrict__ hB, int N) {
  __shared__ float hs[16][32];
  int tid = threadIdx.x;
  int base = blockIdx.x * 16;
  float invN = 1.f / (float)N;
  for (int idx = tid; idx < 512; idx += 256) {
    int nn = idx >> 5, j = idx & 31;
    int n = base + nn;
    float v = 0.f;
    if (n < N) {
      float mu = bnv[j] * invN;
      float var = bnv[32 + j] * invN - mu * mu;
      float is = rsqrtf(var + kEps);
      v = fmaxf((pre[(size_t)n * 32 + j] - mu) * is * gamma[j] + beta[j], 0.f);
      h[(size_t)n * 32 + j] = v;
    }
    hs[nn][j] = v;
  }
  int c = tid & 127, half = tid >> 7;
  int t = c >> 5, g = c & 31;
  float ws[32], wd[32];
  {
    const float* pS = preW + (t * 96 + 32) * 32 + g;
    const float* pD = preW + (t * 96) * 32 + g;
#pragma unroll
    for (int k = 0; k < 32; k++) { ws[k] = pS[k * 32]; wd[k] = pD[k * 32]; }
  }
  float bc = bfv[c];
  __syncthreads();
  {
    int nn = tid >> 4, w = tid & 15;
    int n = base + nn;
    if (n < N) hB[(size_t)n * 16 + w] = packbf(hs[nn][2 * w], hs[nn][2 * w + 1]);
  }
#pragma unroll
  for (int nn = 0; nn < 8; ++nn) {
    int nl = half + 2 * nn;
    int n = base + nl;
    if (n >= N) continue;
    float qa = 0.f, Aa = bc;
#pragma unroll
    for (int k = 0; k < 32; k++) {
      float hk = hs[nl][k];
      qa = fmaf(hk, ws[k], qa);
      Aa = fmaf(hk, wd[k], Aa);
    }
    qB[(size_t)n * 128 + c] = f2bf(qa);
    AB[(size_t)n * 128 + c] = f2bf(Aa);
  }
}

// ---------------- per-layer: fused aggregation (proven R13 structure) ----------------
#define DOTE(F0, F1, UA, UB)                                         \
  F0 = dot2a(ash2(UA.x), w0[0], F0); F1 = dot2a(ash2(UA.x), w1[0], F1); \
  F0 = dot2a(ash2(UA.y), w0[1], F0); F1 = dot2a(ash2(UA.y), w1[1], F1); \
  F0 = dot2a(ash2(UA.z), w0[2], F0); F1 = dot2a(ash2(UA.z), w1[2], F1); \
  F0 = dot2a(ash2(UA.w), w0[3], F0); F1 = dot2a(ash2(UA.w), w1[3], F1); \
  F0 = dot2a(ash2(UB.x), w0[4], F0); F1 = dot2a(ash2(UB.x), w1[4], F1); \
  F0 = dot2a(ash2(UB.y), w0[5], F0); F1 = dot2a(ash2(UB.y), w1[5], F1); \
  F0 = dot2a(ash2(UB.z), w0[6], F0); F1 = dot2a(ash2(UB.z), w1[6], F1); \
  F0 = dot2a(ash2(UB.w), w0[7], F0); F1 = dot2a(ash2(UB.w), w1[7], F1);

#define STATACC(V0, V1)                                                    \
  s0a += V0; sq0 = fmaf(V0, V0, sq0); mn0 = fminf(mn0, V0); mx0 = fmaxf(mx0, V0); \
  s1a += V1; sq1 = fmaf(V1, V1, sq1); mn1 = fminf(mn1, V1); mx1 = fmaxf(mx1, V1);

__global__ __launch_bounds__(256, 4) void agg10b_kernel(
    const unsigned int* __restrict__ qB, const unsigned int* __restrict__ AB,
    const int* __restrict__ coff, const int* __restrict__ srcs,
    const float* __restrict__ ews, const uint4* __restrict__ eg16,
    const float* __restrict__ Wf, unsigned int* __restrict__ stats, int N) {
  int lane = threadIdx.x & 63;
  int wv = (blockIdx.x * blockDim.x + threadIdx.x) >> 6;
  int nwaves = (gridDim.x * blockDim.x) >> 6;
  int t = lane >> 4, g0 = (2 * lane) & 31;
  h2 w0[8], w1[8];
  {
    const float* p = Wf + t * 512 + g0;
#pragma unroll
    for (int k = 0; k < 8; k++) {
      w0[k].x = (_Float16)p[(2 * k) * 32];     w0[k].y = (_Float16)p[(2 * k + 1) * 32];
      w1[k].x = (_Float16)p[(2 * k) * 32 + 1]; w1[k].y = (_Float16)p[(2 * k + 1) * 32 + 1];
    }
  }
  for (int n = wv; n < N; n += nwaves) {
    unsigned int au = AB[(size_t)n * 64 + lane];
    float a0 = bflo(au), a1 = bfhi(au);
    int beg = coff[n], end = coff[n + 1];
    int dg = end - beg;
    float s0a = 0.f, s1a = 0.f, sq0 = 0.f, sq1 = 0.f;
    float mn0 = 1e30f, mn1 = 1e30f, mx0 = -1e30f, mx1 = -1e30f;

    int i = beg;
    unsigned int q0 = 0, q1 = 0, q2 = 0, q3 = 0;
    int sc0 = 0, sc1 = 0, sc2 = 0, sc3 = 0;
    if (i + 4 <= end) {
      int t0 = srcs[i], t1 = srcs[i + 1], t2 = srcs[i + 2], t3 = srcs[i + 3];
      q0 = qB[(size_t)t0 * 64 + lane];
      q1 = qB[(size_t)t1 * 64 + lane];
      q2 = qB[(size_t)t2 * 64 + lane];
      q3 = qB[(size_t)t3 * 64 + lane];
    }
    if (i + 8 <= end) { sc0 = srcs[i + 4]; sc1 = srcs[i + 5]; sc2 = srcs[i + 6]; sc3 = srcs[i + 7]; }
    for (; i + 4 <= end; i += 4) {
      unsigned int nq0 = 0, nq1 = 0, nq2 = 0, nq3 = 0;
      if (i + 8 <= end) {
        nq0 = qB[(size_t)sc0 * 64 + lane];
        nq1 = qB[(size_t)sc1 * 64 + lane];
        nq2 = qB[(size_t)sc2 * 64 + lane];
        nq3 = qB[(size_t)sc3 * 64 + lane];
      }
      float w0s = ews[i], w1s = ews[i + 1], w2s = ews[i + 2], w3s = ews[i + 3];
      const uint4* ep = eg16 + (size_t)i * 2;
      uint4 eA0 = ep[0], eA1 = ep[1], eB0 = ep[2], eB1 = ep[3];
      uint4 eC0 = ep[4], eC1 = ep[5], eD0 = ep[6], eD1 = ep[7];
      if (i + 12 <= end) { sc0 = srcs[i + 8]; sc1 = srcs[i + 9]; sc2 = srcs[i + 10]; sc3 = srcs[i + 11]; }
      float f00 = 0.f, f10 = 0.f, f01 = 0.f, f11 = 0.f;
      float f02 = 0.f, f12 = 0.f, f03 = 0.f, f13 = 0.f;
      DOTE(f00, f10, eA0, eA1)
      DOTE(f01, f11, eB0, eB1)
      DOTE(f02, f12, eC0, eC1)
      DOTE(f03, f13, eD0, eD1)
      float v0, v1;
      v0 = (a0 + bflo(q0) + f00) * w0s; v1 = (a1 + bfhi(q0) + f10) * w0s; STATACC(v0, v1)
      v0 = (a0 + bflo(q1) + f01) * w1s; v1 = (a1 + bfhi(q1) + f11) * w1s; STATACC(v0, v1)
      v0 = (a0 + bflo(q2) + f02) * w2s; v1 = (a1 + bfhi(q2) + f12) * w2s; STATACC(v0, v1)
      v0 = (a0 + bflo(q3) + f03) * w3s; v1 = (a1 + bfhi(q3) + f13) * w3s; STATACC(v0, v1)
      q0 = nq0; q1 = nq1; q2 = nq2; q3 = nq3;
    }
    for (; i < end; ++i) {
      int s = srcs[i];
      unsigned int q = qB[(size_t)s * 64 + lane];
      float w = ews[i];
      const uint4* ep = eg16 + (size_t)i * 2;
      uint4 ea = ep[0], eb = ep[1];
      float f0 = 0.f, f1 = 0.f;
      DOTE(f0, f1, ea, eb)
      float v0 = (a0 + bflo(q) + f0) * w;
      float v1 = (a1 + bfhi(q) + f1) * w;
      STATACC(v0, v1)
    }
    if (dg == 0) { mn0 = 0.f; mx0 = 0.f; mn1 = 0.f; mx1 = 0.f; }
    float inv = 1.f / (float)(dg > 0 ? dg : 1);
    float mean0 = s0a * inv, mean1 = s1a * inv;
    float sd0 = sqrtf(fmaxf(sq0 * inv - mean0 * mean0, 0.f) + kEps);
    float sd1 = sqrtf(fmaxf(sq1 * inv - mean1 * mean1, 0.f) + kEps);
    unsigned int* sp = stats + (size_t)n * 256;
    sp[0 * 64 + lane] = packbf(mean0, mean1);
    sp[1 * 64 + lane] = packbf(mn0, mn1);
    sp[2 * 64 + lane] = packbf(mx0, mx1);
    sp[3 * 64 + lane] = packbf(sd0, sd1);
  }
}

// ---------------- per-layer: MFMA post (S|h @ composed weights) + BN partials ----------------
__global__ __launch_bounds__(256) void postm_kernel(
    const uint4* __restrict__ statsU4, const uint4* __restrict__ hBU4,
    const int* __restrict__ coff, const float* __restrict__ adl,
    const unsigned int* __restrict__ BfragL, const float* __restrict__ bias2,
    float* __restrict__ pre, float* __restrict__ bn, int N, int ntcnt) {
  __shared__ uint4 Bs[6 * 6 * 64];   // 36 KB
  int tid = threadIdx.x, wave = tid >> 6, lane = tid & 63;
  int nt = blockIdx.x * 4 + wave;
  int ntb = nt * 16;
  int ntbC = (nt < ntcnt ? nt : ntcnt - 1) * 16;   // clamped for loads only
  const uint4* Bf4 = (const uint4*)BfragL;

  f32x4v acc[6];
#pragma unroll
  for (int jt = 0; jt < 6; ++jt) { acc[jt].x = 0.f; acc[jt].y = 0.f; acc[jt].z = 0.f; acc[jt].w = 0.f; }

  int ksBase = 0;
  for (int stage = 0; stage < 3; ++stage) {
    int ksN = (stage == 2) ? 5 : 6;
    for (int i = tid; i < 6 * ksN * 64; i += 256) {
      int ln = i & 63, rest = i >> 6;
      int ksl = rest % ksN, jt = rest / ksN;
      Bs[(jt * 6 + ksl) * 64 + ln] = Bf4[(jt * 17 + ksBase + ksl) * 64 + ln];
    }
    __syncthreads();
    for (int ksl = 0; ksl < ksN; ++ksl) {
      int ks = ksBase + ksl;
      uint4 a;
      if (ks < 16) {
        a = statsU4[(size_t)(ntbC + (lane & 15)) * 64 + (ks >> 2) * 16 + (ks & 3) * 4 + (lane >> 4)];
      } else {
        a = hBU4[(size_t)(ntbC + (lane & 15)) * 4 + (lane >> 4)];
      }
#pragma unroll
      for (int jt = 0; jt < 6; ++jt)
        acc[jt] = mfma16(a, Bs[(jt * 6 + ksl) * 64 + lane], acc[jt]);
    }
    __syncthreads();
    ksBase += ksN;
  }

  // epilogue: D layout col=lane&15, row=(lane>>4)*4+reg
  float adv = adl[0] / (float)N;
  int j0 = lane & 15;
  float bs0 = 0.f, bq0 = 0.f, bs1 = 0.f, bq1 = 0.f;
#pragma unroll
  for (int reg = 0; reg < 4; ++reg) {
    int n = ntb + ((lane >> 4) << 2) + reg;
    if (n < N) {
      int dg = coff[n + 1] - coff[n];
      float degc = (float)(dg > 0 ? dg : 1);
      float ld = logf(degc + 1.f);
      float amp = ld / adv, att = adv / ld;
      float v0 = bias2[j0]      + acc[0][reg] + amp * acc[2][reg] + att * acc[4][reg];
      float v1 = bias2[16 + j0] + acc[1][reg] + amp * acc[3][reg] + att * acc[5][reg];
      pre[(size_t)n * 32 + j0] = v0;
      pre[(size_t)n * 32 + 16 + j0] = v1;
      bs0 += v0; bq0 = fmaf(v0, v0, bq0);
      bs1 += v1; bq1 = fmaf(v1, v1, bq1);
    }
  }
  bs0 += __shfl_xor(bs0, 16); bs0 += __shfl_xor(bs0, 32);
  bq0 += __shfl_xor(bq0, 16); bq0 += __shfl_xor(bq0, 32);
  bs1 += __shfl_xor(bs1, 16); bs1 += __shfl_xor(bs1, 32);
  bq1 += __shfl_xor(bq1, 16); bq1 += __shfl_xor(bq1, 32);
  if (lane < 16) {
    atomicAdd(&bn[j0], bs0);
    atomicAdd(&bn[32 + j0], bq0);
    atomicAdd(&bn[16 + j0], bs1);
    atomicAdd(&bn[48 + j0], bq1);
  }
}

// ---------------- fused BN-apply + pooling, then MLP ----------------

__device__ __forceinline__ int lower_bound_dev(const int* a, int n, int key) {
  int lo = 0, hi = n;
  while (lo < hi) {
    int m = (lo + hi) >> 1;
    if (a[m] < key) lo = m + 1; else hi = m;
  }
  return lo;
}

__global__ void pool2_kernel(const float* __restrict__ pre, const float* __restrict__ bnv,
                             const float* __restrict__ gamma, const float* __restrict__ beta,
                             const int* __restrict__ batch, float* __restrict__ gp, int N) {
  int gi = blockIdx.x;  // 64 graphs
  int lo = lower_bound_dev(batch, N, gi);
  int hi = lower_bound_dev(batch, N, gi + 1);
  __shared__ float part[8][32];
  int j = threadIdx.x & 31, ch = threadIdx.x >> 5;
  float invN = 1.f / (float)N;
  float mu = bnv[j] * invN;
  float var = bnv[32 + j] * invN - mu * mu;
  float is = rsqrtf(var + kEps);
  float gm = gamma[j], bt = beta[j];
  float s = 0.f;
  for (int n = lo + ch; n < hi; n += 8)
    s += fmaxf((pre[(size_t)n * 32 + j] - mu) * is * gm + bt, 0.f);
  part[ch][j] = s;
  __syncthreads();
  if (threadIdx.x < 32) {
    float t = 0.f;
    for (int c2 = 0; c2 < 8; c2++) t += part[c2][j];
    gp[gi * 32 + j] = t;
  }
}

__global__ void mlp_kernel(const float* __restrict__ gp,
                           const float* __restrict__ W1, const float* __restrict__ b1,
                           const float* __restrict__ W2, const float* __restrict__ b2,
                           const float* __restrict__ W3, const float* __restrict__ b3,
                           float* __restrict__ out) {
  __shared__ float g1[64 * 32];
  __shared__ float g2[64 * 16];
  int tid = threadIdx.x;  // 256
  for (int i = tid; i < 2048; i += 256) {
    int r = i >> 5, c = i & 31;
    float s = b1[c];
    for (int k = 0; k < 32; k++) s += gp[r * 32 + k] * W1[k * 32 + c];
    g1[i] = fmaxf(s, 0.f);
  }
  __syncthreads();
  for (int i = tid; i < 1024; i += 256) {
    int r = i >> 4, c = i & 15;
    float s = b2[c];
    for (int k = 0; k < 32; k++) s += g1[r * 32 + k] * W2[k * 16 + c];
    g2[i] = fmaxf(s, 0.f);
  }
  __syncthreads();
  if (tid < 64) {
    float s = b3[0];
    for (int k = 0; k < 16; k++) s += g2[tid * 16 + k] * W3[k];
    out[tid] = s;
  }
}

// ---------------- launch ----------------

extern "C" void kernel_launch(void* const* d_in, const int* in_sizes, int n_in,
                              void* d_out, int out_size, void* d_ws, size_t ws_size,
                              hipStream_t stream) {
  (void)n_in; (void)out_size; (void)ws_size;
  const float* x     = (const float*)d_in[0];
  const float* eattr = (const float*)d_in[1];
  const float* ew    = (const float*)d_in[2];
  const int*   eidx  = (const int*)d_in[3];
  const int*   batch = (const int*)d_in[4];
  const float* nodeW = (const float*)d_in[5];
  const float* nodeB = (const float*)d_in[6];
  const float* edgeW = (const float*)d_in[7];
  const float* edgeB = (const float*)d_in[8];
  const float* encW  = (const float*)d_in[9];
  const float* encB  = (const float*)d_in[10];
  const float* preW  = (const float*)d_in[11];
  const float* preB  = (const float*)d_in[12];
  const float* postW = (const float*)d_in[13];
  const float* postB = (const float*)d_in[14];
  const float* linW  = (const float*)d_in[15];
  const float* linB  = (const float*)d_in[16];
  const float* bnG   = (const float*)d_in[17];
  const float* bnB   = (const float*)d_in[18];
  const float* W1    = (const float*)d_in[19];
  const float* b1    = (const float*)d_in[20];
  const float* W2    = (const float*)d_in[21];
  const float* b2    = (const float*)d_in[22];
  const float* W3    = (const float*)d_in[23];
  const float* b3    = (const float*)d_in[24];
  float* out = (float*)d_out;

  int N = in_sizes[0] / 128;
  int E = in_sizes[2];
  const int* srcp = eidx;
  const int* dstp = eidx + E;

  char* wsb = (char*)d_ws;
  size_t woff = 0;
  auto alloc = [&](size_t bytes) -> void* {
    void* p = (void*)(wsb + woff);
    woff += (bytes + 255) & ~(size_t)255;
    return p;
  };
  int* deg   = (int*)alloc((size_t)N * 4);
  int* cnt   = (int*)alloc((size_t)N * 4);
  int* coff  = (int*)alloc((size_t)(N + 1) * 4);
  int* part  = (int*)alloc(64 * 4);
  int* srcs  = (int*)alloc((size_t)E * 4);
  float* ews = (float*)alloc((size_t)E * 4);
  unsigned int* eg16 = (unsigned int*)alloc((size_t)E * 32);
  float* h    = (float*)alloc((size_t)N * 32 * 4);
  float* pre  = (float*)alloc((size_t)N * 32 * 4);
  float* adl  = (float*)alloc(256);
  float* bnbuf = (float*)alloc(2 * 64 * 4);
  float* gp   = (float*)alloc(64 * 32 * 4);
  float* WfB  = (float*)alloc(2 * 4 * 16 * 32 * 4);
  float* bfB  = (float*)alloc(2 * 4 * 32 * 4);
  unsigned short* qB  = (unsigned short*)alloc((size_t)N * 128 * 2);
  unsigned short* AB  = (unsigned short*)alloc((size_t)N * 128 * 2);
  unsigned int* stats = (unsigned int*)alloc((size_t)(N + 16) * 256 * 4);  // padded tile
  unsigned int* hB    = (unsigned int*)alloc((size_t)(N + 16) * 16 * 4);   // bf16 h frags
  unsigned int* Bfrag = (unsigned int*)alloc(2 * 26112 * 4);
  float* bias2 = (float*)alloc(2 * 32 * 4);

  int nb = (N + 1023) / 1024;
  int ntcnt = (N + 15) / 16;
  int grid_pm = (ntcnt + 3) / 4;

  zero_kernel<<<(N + 255) / 256, 256, 0, stream>>>(deg, cnt, bnbuf, N);
  hist_kernel<<<(E + 255) / 256, 256, 0, stream>>>(dstp, deg, E);
  scan1_kernel<<<nb, 1024, 0, stream>>>(deg, coff, part, N);
  scan2_kernel<<<1, 64, 0, stream>>>(part, coff, nb, N);
  scan3_kernel<<<nb, 1024, 0, stream>>>(coff, part, N);
  fill_kernel<<<(E + 255) / 256, 256, 0, stream>>>(srcp, dstp, ew, (const float4*)eattr,
                                                   coff, cnt, srcs, ews, (uint4*)eg16, E);
  adl_kernel<<<1, 1024, 0, stream>>>(deg, adl, N);
  node_emb_kernel<<<(N + 7) / 8, 256, 0, stream>>>(x, nodeW, nodeB, h, N);
  fuse_kernel<<<1, 256, 0, stream>>>(edgeW, edgeB, encW, encB, preW, preB, WfB, bfB);
  fuse2_kernel<<<(2 * 26112 + 255) / 256, 256, 0, stream>>>(postW, postB, linW, linB, Bfrag, bias2);

  // layer 0
  prep_kernel<<<(N + 15) / 16, 256, 0, stream>>>(h, preW, bfB, qB, AB, hB, N);
  agg10b_kernel<<<2048, 256, 0, stream>>>(
      (const unsigned int*)qB, (const unsigned int*)AB, coff, srcs, ews,
      (const uint4*)eg16, WfB, stats, N);
  postm_kernel<<<grid_pm, 256, 0, stream>>>(
      (const uint4*)stats, (const uint4*)hB, coff, adl, Bfrag, bias2,
      pre, bnbuf, N, ntcnt);
  // fused bn_apply(l0) + prep(l1)
  bnprep_kernel<<<(N + 15) / 16, 256, 0, stream>>>(
      pre, bnbuf, bnG, bnB, preW + 12288, bfB + 128, h, qB, AB, hB, N);
  // layer 1
  agg10b_kernel<<<2048, 256, 0, stream>>>(
      (const unsigned int*)qB, (const unsigned int*)AB, coff, srcs, ews,
      (const uint4*)eg16, WfB + 2048, stats, N);
  postm_kernel<<<grid_pm, 256, 0, stream>>>(
      (const uint4*)stats, (const uint4*)hB, coff, adl, Bfrag + 26112, bias2 + 32,
      pre, bnbuf + 64, N, ntcnt);
  // fused bn_apply(l1) + pooling
  pool2_kernel<<<64, 256, 0, stream>>>(pre, bnbuf + 64, bnG + 32, bnB + 32, batch, gp, N);
  mlp_kernel<<<1, 256, 0, stream>>>(gp, W1, b1, W2, b2, W3, b3, out);
}

// Round 16
// 375.057 us; speedup vs baseline: 1.3006x; 1.0333x over previous
//
#include <hip/hip_runtime.h>

constexpr float kEps = 1e-5f;

typedef _Float16 h2 __attribute__((ext_vector_type(2)));
typedef float f2v __attribute__((ext_vector_type(2)));

__device__ __forceinline__ unsigned short f2bf(float x) {
  unsigned int u = __float_as_uint(x);
  unsigned int r = (u + 0x7fffu + ((u >> 16) & 1u)) >> 16;
  return (unsigned short)r;
}
__device__ __forceinline__ float bflo(unsigned int u) { return __uint_as_float(u << 16); }
__device__ __forceinline__ float bfhi(unsigned int u) { return __uint_as_float(u & 0xffff0000u); }
__device__ __forceinline__ unsigned int packbf(float a, float b) {
  return (unsigned int)f2bf(a) | ((unsigned int)f2bf(b) << 16);
}
__device__ __forceinline__ unsigned int pkh2(float a, float b) {
  h2 v; v.x = (_Float16)a; v.y = (_Float16)b;
  return __builtin_bit_cast(unsigned int, v);
}
__device__ __forceinline__ float dot2a(h2 a, h2 b, float c) {
#if __has_builtin(__builtin_amdgcn_fdot2)
  return __builtin_amdgcn_fdot2(a, b, c, false);
#else
  return c + (float)a.x * (float)b.x + (float)a.y * (float)b.y;
#endif
}
__device__ __forceinline__ h2 ash2(unsigned int u) { return __builtin_bit_cast(h2, u); }
__device__ __forceinline__ f2v fma2(f2v a, f2v b, f2v c) { return __builtin_elementwise_fma(a, b, c); }
__device__ __forceinline__ f2v unbf2(unsigned int u) { f2v r; r.x = bflo(u); r.y = bfhi(u); return r; }

// ---------------- setup kernels ----------------

__global__ void zero_kernel(int* __restrict__ a, int* __restrict__ b,
                            float* __restrict__ bnb, int n) {
  int i = blockIdx.x * blockDim.x + threadIdx.x;
  if (i < n) { a[i] = 0; b[i] = 0; }
  if (i < 128) bnb[i] = 0.f;
}

__global__ void hist_kernel(const int* __restrict__ dst, int* __restrict__ deg, int E) {
  int e = blockIdx.x * blockDim.x + threadIdx.x;
  if (e < E) atomicAdd(&deg[dst[e]], 1);
}

__global__ void scan1_kernel(const int* __restrict__ deg, int* __restrict__ off,
                             int* __restrict__ part, int N) {
  __shared__ int sm[1024];
  int i = blockIdx.x * 1024 + threadIdx.x;
  int v = (i < N) ? deg[i] : 0;
  sm[threadIdx.x] = v;
  __syncthreads();
  for (int o = 1; o < 1024; o <<= 1) {
    int t = (threadIdx.x >= o) ? sm[threadIdx.x - o] : 0;
    __syncthreads();
    sm[threadIdx.x] += t;
    __syncthreads();
  }
  if (i < N) off[i] = sm[threadIdx.x] - v;   // exclusive
  if (threadIdx.x == 1023) part[blockIdx.x] = sm[1023];
}

__global__ void scan2_kernel(int* __restrict__ part, int* __restrict__ off, int nb, int N) {
  if (threadIdx.x == 0) {
    int run = 0;
    for (int b = 0; b < nb; b++) { int p = part[b]; part[b] = run; run += p; }
    off[N] = run;
  }
}

__global__ void scan3_kernel(int* __restrict__ off, const int* __restrict__ part, int N) {
  int i = blockIdx.x * 1024 + threadIdx.x;
  if (i < N) off[i] += part[blockIdx.x];
}

// CSR fill: scatter srcs/ews + f16-packed eattr (32B) into slot order (edge
// order within node = atomic arrival order; ulp-level reduction-order only)
__global__ void fill_kernel(const int* __restrict__ src, const int* __restrict__ dst,
                            const float* __restrict__ ew, const float4* __restrict__ eattr4,
                            const int* __restrict__ off, int* __restrict__ cnt,
                            int* __restrict__ srcs, float* __restrict__ ews,
                            uint4* __restrict__ eg16, int E) {
  int e = blockIdx.x * blockDim.x + threadIdx.x;
  if (e < E) {
    int d = dst[e];
    int slot = off[d] + atomicAdd(&cnt[d], 1);
    srcs[slot] = src[e];
    ews[slot] = ew[e];
    float4 a = eattr4[e * 4 + 0], b = eattr4[e * 4 + 1];
    float4 c = eattr4[e * 4 + 2], q = eattr4[e * 4 + 3];
    uint4 u0, u1;
    u0.x = pkh2(a.x, a.y); u0.y = pkh2(a.z, a.w);
    u0.z = pkh2(b.x, b.y); u0.w = pkh2(b.z, b.w);
    u1.x = pkh2(c.x, c.y); u1.y = pkh2(c.z, c.w);
    u1.z = pkh2(q.x, q.y); u1.w = pkh2(q.z, q.w);
    eg16[(size_t)slot * 2 + 0] = u0;
    eg16[(size_t)slot * 2 + 1] = u1;
  }
}

__global__ void adl_kernel(const int* __restrict__ deg, float* __restrict__ adl, int N) {
  __shared__ float sm[1024];
  float s = 0.f;
  for (int n = threadIdx.x; n < N; n += 1024) s += logf((float)deg[n] + 1.f);
  sm[threadIdx.x] = s;
  __syncthreads();
  for (int o = 512; o > 0; o >>= 1) {
    if (threadIdx.x < o) sm[threadIdx.x] += sm[threadIdx.x + o];
    __syncthreads();
  }
  if (threadIdx.x == 0) adl[0] = sm[0];   // sum of log(deg+1); consumers divide by N
}

// h0 = x @ node_W + node_b   (x: [N,128], W: [128,32])
__global__ void node_emb_kernel(const float* __restrict__ x, const float* __restrict__ W,
                                const float* __restrict__ b, float* __restrict__ h, int N) {
  int n = blockIdx.x * 8 + (threadIdx.x >> 5);
  int j = threadIdx.x & 31;
  if (n >= N) return;
  float acc = b[j];
  const float4* x4 = (const float4*)(x + (size_t)n * 128);
#pragma unroll
  for (int q = 0; q < 32; q++) {
    float4 v = x4[q];
    acc += v.x * W[(4 * q + 0) * 32 + j];
    acc += v.y * W[(4 * q + 1) * 32 + j];
    acc += v.z * W[(4 * q + 2) * 32 + j];
    acc += v.w * W[(4 * q + 3) * 32 + j];
  }
  h[n * 32 + j] = acc;
}

// Fold edge path: Wf[l,t] = (edge_W @ enc_W[l]) @ pre_W[l,t,64:96,:]  (16x32)
__global__ void fuse_kernel(const float* __restrict__ edge_W, const float* __restrict__ edge_b,
                            const float* __restrict__ enc_W, const float* __restrict__ enc_b,
                            const float* __restrict__ pre_W, const float* __restrict__ pre_b,
                            float* __restrict__ Wf, float* __restrict__ bf) {
  __shared__ float tW[2][16][32];
  __shared__ float tb[2][32];
  int tid = threadIdx.x;
  for (int i = tid; i < 1024; i += 256) {
    int l = i >> 9, r = (i >> 5) & 15, c = i & 31;
    float s = 0.f;
    for (int k = 0; k < 32; k++) s += edge_W[r * 32 + k] * enc_W[(l * 32 + k) * 32 + c];
    tW[l][r][c] = s;
  }
  for (int i = tid; i < 64; i += 256) {
    int l = i >> 5, c = i & 31;
    float s = enc_b[l * 32 + c];
    for (int k = 0; k < 32; k++) s += edge_b[k] * enc_W[(l * 32 + k) * 32 + c];
    tb[l][c] = s;
  }
  __syncthreads();
  for (int i = tid; i < 4096; i += 256) {
    int l = i >> 11, t = (i >> 9) & 3, r = (i >> 5) & 15, c = i & 31;
    float s = 0.f;
    for (int k = 0; k < 32; k++) s += tW[l][r][k] * pre_W[((l * 4 + t) * 96 + 64 + k) * 32 + c];
    Wf[i] = s;
  }
  for (int i = tid; i < 256; i += 256) {
    int l = i >> 7, t = (i >> 5) & 3, c = i & 31;
    float s = pre_b[(l * 4 + t) * 32 + c];
    for (int k = 0; k < 32; k++) s += tb[l][k] * pre_W[((l * 4 + t) * 96 + 64 + k) * 32 + c];
    bf[i] = s;
  }
}

// ---------------- per-layer: node pre-projection ----------------
__global__ __launch_bounds__(256) void prep_kernel(
    const float* __restrict__ h, const float* __restrict__ preW,
    const float* __restrict__ bfv, unsigned short* __restrict__ qB,
    unsigned short* __restrict__ AB, int N) {
  __shared__ float hs[16][32];
  int tid = threadIdx.x;
  int c = tid & 127, half = tid >> 7;
  int t = c >> 5, g = c & 31;
  float ws[32], wd[32];
  {
    const float* pS = preW + (t * 96 + 32) * 32 + g;
    const float* pD = preW + (t * 96) * 32 + g;
#pragma unroll
    for (int k = 0; k < 32; k++) { ws[k] = pS[k * 32]; wd[k] = pD[k * 32]; }
  }
  float bc = bfv[c];
  int base = blockIdx.x * 16;
  for (int i = tid; i < 512; i += 256) {
    int nn = i >> 5;
    hs[nn][i & 31] = (base + nn < N) ? h[(size_t)(base + nn) * 32 + (i & 31)] : 0.f;
  }
  __syncthreads();
#pragma unroll
  for (int nn = 0; nn < 8; ++nn) {
    int nl = half + 2 * nn;
    int n = base + nl;
    if (n >= N) continue;
    float qa = 0.f, Aa = bc;
#pragma unroll
    for (int k = 0; k < 32; k++) {
      float hk = hs[nl][k];
      qa = fmaf(hk, ws[k], qa);
      Aa = fmaf(hk, wd[k], Aa);
    }
    qB[(size_t)n * 128 + c] = f2bf(qa);
    AB[(size_t)n * 128 + c] = f2bf(Aa);
  }
}

// ---------------- fused BN-apply + next-layer pre-projection ----------------
__global__ __launch_bounds__(256) void bnprep_kernel(
    const float* __restrict__ pre, const float* __restrict__ bnv,
    const float* __restrict__ gamma, const float* __restrict__ beta,
    const float* __restrict__ preW, const float* __restrict__ bfv,
    float* __restrict__ h, unsigned short* __restrict__ qB,
    unsigned short* __restrict__ AB, int N) {
  __shared__ float hs[16][32];
  int tid = threadIdx.x;
  int base = blockIdx.x * 16;
  float invN = 1.f / (float)N;
  for (int idx = tid; idx < 512; idx += 256) {
    int nn = idx >> 5, j = idx & 31;
    int n = base + nn;
    float v = 0.f;
    if (n < N) {
      float mu = bnv[j] * invN;
      float var = bnv[32 + j] * invN - mu * mu;
      float is = rsqrtf(var + kEps);
      v = fmaxf((pre[(size_t)n * 32 + j] - mu) * is * gamma[j] + beta[j], 0.f);
      h[(size_t)n * 32 + j] = v;
    }
    hs[nn][j] = v;
  }
  int c = tid & 127, half = tid >> 7;
  int t = c >> 5, g = c & 31;
  float ws[32], wd[32];
  {
    const float* pS = preW + (t * 96 + 32) * 32 + g;
    const float* pD = preW + (t * 96) * 32 + g;
#pragma unroll
    for (int k = 0; k < 32; k++) { ws[k] = pS[k * 32]; wd[k] = pD[k * 32]; }
  }
  float bc = bfv[c];
  __syncthreads();
#pragma unroll
  for (int nn = 0; nn < 8; ++nn) {
    int nl = half + 2 * nn;
    int n = base + nl;
    if (n >= N) continue;
    float qa = 0.f, Aa = bc;
#pragma unroll
    for (int k = 0; k < 32; k++) {
      float hk = hs[nl][k];
      qa = fmaf(hk, ws[k], qa);
      Aa = fmaf(hk, wd[k], Aa);
    }
    qB[(size_t)n * 128 + c] = f2bf(qa);
    AB[(size_t)n * 128 + c] = f2bf(Aa);
  }
}

// ---------------- per-layer: fused aggregation (grid-stride waves, hoisted weights) ----------------
#define DOTE(F0, F1, UA, UB)                                         \
  F0 = dot2a(ash2(UA.x), w0[0], F0); F1 = dot2a(ash2(UA.x), w1[0], F1); \
  F0 = dot2a(ash2(UA.y), w0[1], F0); F1 = dot2a(ash2(UA.y), w1[1], F1); \
  F0 = dot2a(ash2(UA.z), w0[2], F0); F1 = dot2a(ash2(UA.z), w1[2], F1); \
  F0 = dot2a(ash2(UA.w), w0[3], F0); F1 = dot2a(ash2(UA.w), w1[3], F1); \
  F0 = dot2a(ash2(UB.x), w0[4], F0); F1 = dot2a(ash2(UB.x), w1[4], F1); \
  F0 = dot2a(ash2(UB.y), w0[5], F0); F1 = dot2a(ash2(UB.y), w1[5], F1); \
  F0 = dot2a(ash2(UB.z), w0[6], F0); F1 = dot2a(ash2(UB.z), w1[6], F1); \
  F0 = dot2a(ash2(UB.w), w0[7], F0); F1 = dot2a(ash2(UB.w), w1[7], F1);

#define STATACC(V0, V1)                                                    \
  s0a += V0; sq0 = fmaf(V0, V0, sq0); mn0 = fminf(mn0, V0); mx0 = fmaxf(mx0, V0); \
  s1a += V1; sq1 = fmaf(V1, V1, sq1); mn1 = fminf(mn1, V1); mx1 = fmaxf(mx1, V1);

__global__ __launch_bounds__(256, 4) void agg10b_kernel(
    const unsigned int* __restrict__ qB, const unsigned int* __restrict__ AB,
    const int* __restrict__ coff, const int* __restrict__ srcs,
    const float* __restrict__ ews, const uint4* __restrict__ eg16,
    const float* __restrict__ Wf, unsigned int* __restrict__ stats, int N) {
  int lane = threadIdx.x & 63;
  int wv = (blockIdx.x * blockDim.x + threadIdx.x) >> 6;
  int nwaves = (gridDim.x * blockDim.x) >> 6;
  int t = lane >> 4, g0 = (2 * lane) & 31;
  h2 w0[8], w1[8];
  {
    const float* p = Wf + t * 512 + g0;
#pragma unroll
    for (int k = 0; k < 8; k++) {
      w0[k].x = (_Float16)p[(2 * k) * 32];     w0[k].y = (_Float16)p[(2 * k + 1) * 32];
      w1[k].x = (_Float16)p[(2 * k) * 32 + 1]; w1[k].y = (_Float16)p[(2 * k + 1) * 32 + 1];
    }
  }
  for (int n = wv; n < N; n += nwaves) {
    unsigned int au = AB[(size_t)n * 64 + lane];
    float a0 = bflo(au), a1 = bfhi(au);
    int beg = coff[n], end = coff[n + 1];
    int dg = end - beg;
    float s0a = 0.f, s1a = 0.f, sq0 = 0.f, sq1 = 0.f;
    float mn0 = 1e30f, mn1 = 1e30f, mx0 = -1e30f, mx1 = -1e30f;

    int i = beg;
    unsigned int q0 = 0, q1 = 0, q2 = 0, q3 = 0;
    int sc0 = 0, sc1 = 0, sc2 = 0, sc3 = 0;
    if (i + 4 <= end) {
      int t0 = srcs[i], t1 = srcs[i + 1], t2 = srcs[i + 2], t3 = srcs[i + 3];
      q0 = qB[(size_t)t0 * 64 + lane];
      q1 = qB[(size_t)t1 * 64 + lane];
      q2 = qB[(size_t)t2 * 64 + lane];
      q3 = qB[(size_t)t3 * 64 + lane];
    }
    if (i + 8 <= end) { sc0 = srcs[i + 4]; sc1 = srcs[i + 5]; sc2 = srcs[i + 6]; sc3 = srcs[i + 7]; }
    for (; i + 4 <= end; i += 4) {
      // issue q-gathers for the NEXT batch first (one full iteration of latency hiding)
      unsigned int nq0 = 0, nq1 = 0, nq2 = 0, nq3 = 0;
      if (i + 8 <= end) {
        nq0 = qB[(size_t)sc0 * 64 + lane];
        nq1 = qB[(size_t)sc1 * 64 + lane];
        nq2 = qB[(size_t)sc2 * 64 + lane];
        nq3 = qB[(size_t)sc3 * 64 + lane];
      }
      float w0s = ews[i], w1s = ews[i + 1], w2s = ews[i + 2], w3s = ews[i + 3];
      const uint4* ep = eg16 + (size_t)i * 2;
      uint4 eA0 = ep[0], eA1 = ep[1], eB0 = ep[2], eB1 = ep[3];
      uint4 eC0 = ep[4], eC1 = ep[5], eD0 = ep[6], eD1 = ep[7];
      if (i + 12 <= end) { sc0 = srcs[i + 8]; sc1 = srcs[i + 9]; sc2 = srcs[i + 10]; sc3 = srcs[i + 11]; }
      float f00 = 0.f, f10 = 0.f, f01 = 0.f, f11 = 0.f;
      float f02 = 0.f, f12 = 0.f, f03 = 0.f, f13 = 0.f;
      DOTE(f00, f10, eA0, eA1)
      DOTE(f01, f11, eB0, eB1)
      DOTE(f02, f12, eC0, eC1)
      DOTE(f03, f13, eD0, eD1)
      float v0, v1;
      v0 = (a0 + bflo(q0) + f00) * w0s; v1 = (a1 + bfhi(q0) + f10) * w0s; STATACC(v0, v1)
      v0 = (a0 + bflo(q1) + f01) * w1s; v1 = (a1 + bfhi(q1) + f11) * w1s; STATACC(v0, v1)
      v0 = (a0 + bflo(q2) + f02) * w2s; v1 = (a1 + bfhi(q2) + f12) * w2s; STATACC(v0, v1)
      v0 = (a0 + bflo(q3) + f03) * w3s; v1 = (a1 + bfhi(q3) + f13) * w3s; STATACC(v0, v1)
      q0 = nq0; q1 = nq1; q2 = nq2; q3 = nq3;
    }
    for (; i < end; ++i) {
      int s = srcs[i];
      unsigned int q = qB[(size_t)s * 64 + lane];
      float w = ews[i];
      const uint4* ep = eg16 + (size_t)i * 2;
      uint4 ea = ep[0], eb = ep[1];
      float f0 = 0.f, f1 = 0.f;
      DOTE(f0, f1, ea, eb)
      float v0 = (a0 + bflo(q) + f0) * w;
      float v1 = (a1 + bfhi(q) + f1) * w;
      STATACC(v0, v1)
    }
    if (dg == 0) { mn0 = 0.f; mx0 = 0.f; mn1 = 0.f; mx1 = 0.f; }
    float inv = 1.f / (float)(dg > 0 ? dg : 1);
    float mean0 = s0a * inv, mean1 = s1a * inv;
    float sd0 = sqrtf(fmaxf(sq0 * inv - mean0 * mean0, 0.f) + kEps);
    float sd1 = sqrtf(fmaxf(sq1 * inv - mean1 * mean1, 0.f) + kEps);
    unsigned int* sp = stats + (size_t)n * 256;
    sp[0 * 64 + lane] = packbf(mean0, mean1);
    sp[1 * 64 + lane] = packbf(mn0, mn1);
    sp[2 * 64 + lane] = packbf(mx0, mx1);
    sp[3 * 64 + lane] = packbf(sd0, sd1);
  }
}

// ---------------- per-layer: post_nn + lin + BN partials ----------------
// ym/ya/yt decomposition: three packed dot products (v_pk_fma_f32), amp/att
// applied once per node. Grid 640 so LDS staging amortizes over ~39 nodes.
__global__ __launch_bounds__(256) void post_kernel(
    const float* __restrict__ h, const unsigned int* __restrict__ stats,
    const int* __restrict__ coff, const float* __restrict__ adl,
    const float* __restrict__ postW, const float* __restrict__ postB,
    const float* __restrict__ linW, const float* __restrict__ linB,
    float* __restrict__ pre, float* __restrict__ bn, int N) {
  __shared__ unsigned int pwp[208 * 32];   // rows paired (2r,2r+1): 26 KB
  __shared__ unsigned int stu[4][256];     // per-wave raw stats rows: 4 KB
  __shared__ float red[8][32];             // BN partial reduce: 1 KB
  int tid = threadIdx.x;
  for (int i = tid; i < 6656; i += 256) {
    int r = i >> 5, cc = i & 31, tP = cc >> 3, gq = cc & 7;
    float lo = postW[tP * 3328 + (2 * r) * 8 + gq];
    float hi = postW[tP * 3328 + (2 * r + 1) * 8 + gq];
    pwp[i] = packbf(lo, hi);
  }
  __syncthreads();

  int wave = tid >> 6, lane = tid & 63;
  int c = lane & 31, hh = lane >> 5;
  int tP = c >> 3;
  float adN = adl[0];
  float bs = 0.f, bq = 0.f;

  for (int n = blockIdx.x * 4 + wave; n < N; n += gridDim.x * 4) {
    {
      uint4 su = ((const uint4*)stats)[(size_t)n * 64 + lane];
      ((uint4*)stu[wave])[lane] = su;   // per-wave region: no block barrier needed
    }
    int dg = coff[n + 1] - coff[n];
    float degc = (float)(dg > 0 ? dg : 1);
    float ad = adN / (float)N;
    float ld = logf(degc + 1.f);
    float amp = ld / ad, att = ad / ld;

    float acc = (hh == 0) ? postB[tP * 8 + (c & 7)] : 0.f;
    const float4* h4 = (const float4*)(h + (size_t)n * 32);
#pragma unroll
    for (int q4 = 0; q4 < 4; q4++) {
      float4 hv = h4[hh * 4 + q4];
      int r0 = hh * 8 + q4 * 2;
      unsigned int u0 = pwp[r0 * 32 + c], u1 = pwp[(r0 + 1) * 32 + c];
      acc = fmaf(hv.x, bflo(u0), acc);
      acc = fmaf(hv.y, bfhi(u0), acc);
      acc = fmaf(hv.z, bflo(u1), acc);
      acc = fmaf(hv.w, bfhi(u1), acc);
    }
    f2v ym, ya, yt;
    ym.x = 0.f; ym.y = 0.f; ya = ym; yt = ym;
#pragma unroll 8
    for (int jj = 0; jj < 32; jj++) {
      int sIdx = hh * 2 + (jj >> 4);
      unsigned int sv = stu[wave][sIdx * 64 + tP * 16 + (jj & 15)];
      f2v v2 = unbf2(sv);
      int rm = 16 + hh * 32 + jj;
      f2v um = unbf2(pwp[rm * 32 + c]);
      f2v ua = unbf2(pwp[(rm + 64) * 32 + c]);
      f2v ut = unbf2(pwp[(rm + 128) * 32 + c]);
      ym = fma2(v2, um, ym);
      ya = fma2(v2, ua, ya);
      yt = fma2(v2, ut, yt);
    }
    acc += ym.x + ym.y;
    acc = fmaf(amp, ya.x + ya.y, acc);
    acc = fmaf(att, yt.x + yt.y, acc);
    acc += __shfl_xor(acc, 32);
    float o = linB[c];
#pragma unroll
    for (int k = 0; k < 32; k++) {
      float a = __shfl(acc, k);
      o = fmaf(a, linW[k * 32 + c], o);
    }
    if (lane < 32) {
      pre[(size_t)n * 32 + c] = o;
      bs += o;
      bq = fmaf(o, o, bq);
    }
  }

  __syncthreads();
  if (lane < 32) {
    red[wave * 2 + 0][c] = bs;
    red[wave * 2 + 1][c] = bq;
  }
  __syncthreads();
  if (tid < 64) {
    int which = tid >> 5, cc = tid & 31;
    float s = red[0 * 2 + which][cc] + red[1 * 2 + which][cc] +
              red[2 * 2 + which][cc] + red[3 * 2 + which][cc];
    atomicAdd(&bn[which * 32 + cc], s);
  }
}

// ---------------- fused BN-apply + pooling, then MLP ----------------

__device__ __forceinline__ int lower_bound_dev(const int* a, int n, int key) {
  int lo = 0, hi = n;
  while (lo < hi) {
    int m = (lo + hi) >> 1;
    if (a[m] < key) lo = m + 1; else hi = m;
  }
  return lo;
}

__global__ void pool2_kernel(const float* __restrict__ pre, const float* __restrict__ bnv,
                             const float* __restrict__ gamma, const float* __restrict__ beta,
                             const int* __restrict__ batch, float* __restrict__ gp, int N) {
  int gi = blockIdx.x;  // 64 graphs
  int lo = lower_bound_dev(batch, N, gi);
  int hi = lower_bound_dev(batch, N, gi + 1);
  __shared__ float part[8][32];
  int j = threadIdx.x & 31, ch = threadIdx.x >> 5;
  float invN = 1.f / (float)N;
  float mu = bnv[j] * invN;
  float var = bnv[32 + j] * invN - mu * mu;
  float is = rsqrtf(var + kEps);
  float gm = gamma[j], bt = beta[j];
  float s = 0.f;
  for (int n = lo + ch; n < hi; n += 8)
    s += fmaxf((pre[(size_t)n * 32 + j] - mu) * is * gm + bt, 0.f);
  part[ch][j] = s;
  __syncthreads();
  if (threadIdx.x < 32) {
    float t = 0.f;
    for (int c2 = 0; c2 < 8; c2++) t += part[c2][j];
    gp[gi * 32 + j] = t;
  }
}

__global__ void mlp_kernel(const float* __restrict__ gp,
                           const float* __restrict__ W1, const float* __restrict__ b1,
                           const float* __restrict__ W2, const float* __restrict__ b2,
                           const float* __restrict__ W3, const float* __restrict__ b3,
                           float* __restrict__ out) {
  __shared__ float g1[64 * 32];
  __shared__ float g2[64 * 16];
  int tid = threadIdx.x;  // 256
  for (int i = tid; i < 2048; i += 256) {
    int r = i >> 5, c = i & 31;
    float s = b1[c];
    for (int k = 0; k < 32; k++) s += gp[r * 32 + k] * W1[k * 32 + c];
    g1[i] = fmaxf(s, 0.f);
  }
  __syncthreads();
  for (int i = tid; i < 1024; i += 256) {
    int r = i >> 4, c = i & 15;
    float s = b2[c];
    for (int k = 0; k < 32; k++) s += g1[r * 32 + k] * W2[k * 16 + c];
    g2[i] = fmaxf(s, 0.f);
  }
  __syncthreads();
  if (tid < 64) {
    float s = b3[0];
    for (int k = 0; k < 16; k++) s += g2[tid * 16 + k] * W3[k];
    out[tid] = s;
  }
}

// ---------------- launch ----------------

extern "C" void kernel_launch(void* const* d_in, const int* in_sizes, int n_in,
                              void* d_out, int out_size, void* d_ws, size_t ws_size,
                              hipStream_t stream) {
  (void)n_in; (void)out_size; (void)ws_size;
  const float* x     = (const float*)d_in[0];
  const float* eattr = (const float*)d_in[1];
  const float* ew    = (const float*)d_in[2];
  const int*   eidx  = (const int*)d_in[3];
  const int*   batch = (const int*)d_in[4];
  const float* nodeW = (const float*)d_in[5];
  const float* nodeB = (const float*)d_in[6];
  const float* edgeW = (const float*)d_in[7];
  const float* edgeB = (const float*)d_in[8];
  const float* encW  = (const float*)d_in[9];
  const float* encB  = (const float*)d_in[10];
  const float* preW  = (const float*)d_in[11];
  const float* preB  = (const float*)d_in[12];
  const float* postW = (const float*)d_in[13];
  const float* postB = (const float*)d_in[14];
  const float* linW  = (const float*)d_in[15];
  const float* linB  = (const float*)d_in[16];
  const float* bnG   = (const float*)d_in[17];
  const float* bnB   = (const float*)d_in[18];
  const float* W1    = (const float*)d_in[19];
  const float* b1    = (const float*)d_in[20];
  const float* W2    = (const float*)d_in[21];
  const float* b2    = (const float*)d_in[22];
  const float* W3    = (const float*)d_in[23];
  const float* b3    = (const float*)d_in[24];
  float* out = (float*)d_out;

  int N = in_sizes[0] / 128;
  int E = in_sizes[2];
  const int* srcp = eidx;
  const int* dstp = eidx + E;

  char* wsb = (char*)d_ws;
  size_t woff = 0;
  auto alloc = [&](size_t bytes) -> void* {
    void* p = (void*)(wsb + woff);
    woff += (bytes + 255) & ~(size_t)255;
    return p;
  };
  int* deg   = (int*)alloc((size_t)N * 4);
  int* cnt   = (int*)alloc((size_t)N * 4);
  int* coff  = (int*)alloc((size_t)(N + 1) * 4);
  int* part  = (int*)alloc(64 * 4);
  int* srcs  = (int*)alloc((size_t)E * 4);
  float* ews = (float*)alloc((size_t)E * 4);
  unsigned int* eg16 = (unsigned int*)alloc((size_t)E * 32);  // f16-packed eattr, slot order
  float* h    = (float*)alloc((size_t)N * 32 * 4);
  float* pre  = (float*)alloc((size_t)N * 32 * 4);
  float* adl  = (float*)alloc(256);
  float* bnbuf = (float*)alloc(2 * 64 * 4);
  float* gp   = (float*)alloc(64 * 32 * 4);
  float* WfB  = (float*)alloc(2 * 4 * 16 * 32 * 4);
  float* bfB  = (float*)alloc(2 * 4 * 32 * 4);
  unsigned short* qB  = (unsigned short*)alloc((size_t)N * 128 * 2);
  unsigned short* AB  = (unsigned short*)alloc((size_t)N * 128 * 2);
  unsigned int* stats = (unsigned int*)alloc((size_t)N * 256 * 4);

  int nb = (N + 1023) / 1024;
  zero_kernel<<<(N + 255) / 256, 256, 0, stream>>>(deg, cnt, bnbuf, N);
  hist_kernel<<<(E + 255) / 256, 256, 0, stream>>>(dstp, deg, E);
  scan1_kernel<<<nb, 1024, 0, stream>>>(deg, coff, part, N);
  scan2_kernel<<<1, 64, 0, stream>>>(part, coff, nb, N);
  scan3_kernel<<<nb, 1024, 0, stream>>>(coff, part, N);
  fill_kernel<<<(E + 255) / 256, 256, 0, stream>>>(srcp, dstp, ew, (const float4*)eattr,
                                                   coff, cnt, srcs, ews, (uint4*)eg16, E);
  adl_kernel<<<1, 1024, 0, stream>>>(deg, adl, N);
  node_emb_kernel<<<(N + 7) / 8, 256, 0, stream>>>(x, nodeW, nodeB, h, N);
  fuse_kernel<<<1, 256, 0, stream>>>(edgeW, edgeB, encW, encB, preW, preB, WfB, bfB);

  // layer 0
  prep_kernel<<<(N + 15) / 16, 256, 0, stream>>>(h, preW, bfB, qB, AB, N);
  agg10b_kernel<<<2048, 256, 0, stream>>>(
      (const unsigned int*)qB, (const unsigned int*)AB, coff, srcs, ews,
      (const uint4*)eg16, WfB, stats, N);
  post_kernel<<<640, 256, 0, stream>>>(
      h, stats, coff, adl, postW, postB, linW, linB, pre, bnbuf, N);
  // fused bn_apply(l0) + prep(l1)
  bnprep_kernel<<<(N + 15) / 16, 256, 0, stream>>>(
      pre, bnbuf, bnG, bnB, preW + 12288, bfB + 128, h, qB, AB, N);
  // layer 1
  agg10b_kernel<<<2048, 256, 0, stream>>>(
      (const unsigned int*)qB, (const unsigned int*)AB, coff, srcs, ews,
      (const uint4*)eg16, WfB + 2048, stats, N);
  post_kernel<<<640, 256, 0, stream>>>(
      h, stats, coff, adl, postW + 13312, postB + 32, linW + 1024, linB + 32,
      pre, bnbuf + 64, N);
  // fused bn_apply(l1) + pooling
  pool2_kernel<<<64, 256, 0, stream>>>(pre, bnbuf + 64, bnG + 32, bnB + 32, batch, gp, N);
  mlp_kernel<<<1, 256, 0, stream>>>(gp, W1, b1, W2, b2, W3, b3, out);
}